// Round 13
// baseline (486.446 us; speedup 1.0000x reference)
//
#include <hip/hip_runtime.h>
#include <hip/hip_bf16.h>
#include <math.h>

#define WSZ 7
#define NTOK 49
#define CH 96
#define HIMG 224
#define WIMG 224
#define HWIMG (224*224)
#define SHIFT_ 3
#define HID 384

typedef __attribute__((ext_vector_type(8))) short bf16x8;
typedef __attribute__((ext_vector_type(4))) float f32x4;
typedef unsigned int u32;
typedef unsigned short u16;

__device__ __forceinline__ u32 pk2(float a, float b) {
    u16 ua = __builtin_bit_cast(u16, __float2bfloat16(a));
    u16 ub = __builtin_bit_cast(u16, __float2bfloat16(b));
    return (u32)ua | ((u32)ub << 16);
}
__device__ __forceinline__ float bflo(u32 u) { return __builtin_bit_cast(float, u << 16); }
__device__ __forceinline__ float bfhi(u32 u) { return __builtin_bit_cast(float, u & 0xFFFF0000u); }

union FragU { u32 w[4]; bf16x8 v; };

// regroup: C'-frags of two 16-row tiles (rows g*4+r, cols l15) -> A/B-frag
__device__ __forceinline__ bf16x8 regroup(u32 t0w0, u32 t0w1, u32 t1w0, u32 t1w1, int lane) {
    int sl0 = (lane & 15) + ((lane & 16) << 1);
    int sl1 = sl0 + 16;
    u32 x0 = (u32)__shfl((int)t0w0, sl0);
    u32 y0 = (u32)__shfl((int)t1w0, sl0);
    u32 x1 = (u32)__shfl((int)t0w1, sl0);
    u32 y1 = (u32)__shfl((int)t1w1, sl0);
    u32 x2 = (u32)__shfl((int)t0w0, sl1);
    u32 y2 = (u32)__shfl((int)t1w0, sl1);
    u32 x3 = (u32)__shfl((int)t0w1, sl1);
    u32 y3 = (u32)__shfl((int)t1w1, sl1);
    bool lo = lane < 32;
    FragU f;
    f.w[0] = lo ? x0 : y0;
    f.w[1] = lo ? x1 : y1;
    f.w[2] = lo ? x2 : y2;
    f.w[3] = lo ? x3 : y3;
    return f.v;
}

// tanh-approx GELU as x*sigmoid(2s): no division.
__device__ __forceinline__ float gelu_f(float x) {
    float x2 = x * x;
    float t  = x * (1.5957691216057308f + 0.07135481283587191f * x2);
    float e  = __expf(t);
    float r  = __builtin_amdgcn_rcpf(e + 1.0f);
    return x - x * r;
}

// ---------- prep (round-7 proven) ----------
__global__ __launch_bounds__(256) void prep_kernel(
    const float* __restrict__ w1, const float* __restrict__ w2,
    const float* __restrict__ pw, const float* __restrict__ qw,
    __hip_bfloat16* __restrict__ ws, int n)
{
    int i = blockIdx.x * 256 + threadIdx.x;
    if (i >= n) return;
    float val = 0.f;
    if (i < 81920) {
        int ch = i / 20480, r = i - ch * 20480;
        int half = r / 10240;
        int rr = r - half * 10240;
        if (rr < 9984) {
            int row = rr / 104, col = rr - row * 104;
            if (col < 96)
                val = (half == 0) ? w1[col * HID + ch * 96 + row]
                                  : w2[(size_t)(ch * 96 + col) * CH + row];
        }
    } else if (i < 92160) {
        int r = i - 81920;
        if (r < 9984) {
            int row = r / 104, col = r - row * 104;
            if (col < 96) val = pw[col * CH + row];
        }
    } else {
        int j = i - 92160;
        int hh = j / 9984, rr = j - hh * 9984;
        int dp = rr / 104, c = rr - dp * 104;
        if (c < 96) {
            int colW = (dp < 32) ? (hh * 32 + dp)
                     : (dp < 64) ? (96 + hh * 32 + dp - 32)
                                 : (192 + hh * 32 + dp - 64);
            val = qw[c * 288 + colW];
        }
    }
    ws[i] = __float2bfloat16(val);
}

// ========== K1 v7: 3-slab LN1 staging (34.8KB LDS), no reg clamp, round-10 bias path ==========
__global__ __launch_bounds__(256) void attn2_kernel(
    const float* __restrict__ x,
    const float* __restrict__ g1, const float* __restrict__ b1,
    const __hip_bfloat16* __restrict__ wsW,
    const float* __restrict__ qkv_b, const float* __restrict__ pb,
    const float* __restrict__ btab,
    __hip_bfloat16* __restrict__ projout)
{
    const int tid  = threadIdx.x;
    const int lane = tid & 63;
    const int wv   = tid >> 6;
    const int l15  = lane & 15;
    const int g    = lane >> 4;
    const int bi   = blockIdx.x;
    const int b    = bi >> 8;            // 256 blocks per image
    const int wh   = (bi >> 3) & 31;
    const int ww0  = (bi & 7) * 4;       // first of 4 windows
    const int ww   = ww0 + wv;

    __shared__ float btabL[512];
    __shared__ __align__(16) __hip_bfloat16 slab[32][7][32];    // 14336B
    __shared__ __align__(16) char uniA[4][4608];                // per-wave vT / proj scratch

    __hip_bfloat16 (*vT)[72] = (__hip_bfloat16(*)[72])uniA[wv];
    u32* prS = (u32*)uniA[wv];

    for (int idx = tid; idx < 507; idx += 256) btabL[idx] = btab[idx];

    const int colBase = ww0 * 7 + 3;
    const int cb4 = (colBase & ~3) >> 2;
    const int a0  = colBase & 3;

    // ---- per-it token geometry ----
    int yiA[4], scA[4]; bool realA[4];
    #pragma unroll
    for (int it = 0; it < 4; ++it) {
        int i = it * 16 + l15;
        realA[it] = i < NTOK;
        int yi = i / 7, xi = i - yi * 7;
        yiA[it] = yi; scA[it] = a0 + wv * 7 + xi;
    }

    // ---- LN1: 3 slab passes; raws kept as packed pre-norm bf16 + f32 stats ----
    float s0a[4] = {0.f, 0.f, 0.f, 0.f}, s1a[4] = {0.f, 0.f, 0.f, 0.f};
    FragU xf[4][3];

    for (int ks = 0; ks < 3; ++ks) {
        #pragma unroll
        for (int k = 0; k < 7; ++k) {    // 32ch*7rows*8 float4 = 1792 / 256
            int idx = tid + 256 * k;
            int c = idx / 56, rem = idx - c * 56;
            int r = rem >> 3, cf = rem & 7;
            int gr = wh * 7 + 3 + r; if (gr >= HIMG) gr -= HIMG;
            int g4 = cb4 + cf; if (g4 >= 56) g4 -= 56;
            float4 v = *(const float4*)(x + ((size_t)(b * CH + ks * 32 + c) * HIMG + gr) * WIMG + g4 * 4);
            uint2 pk;
            pk.x = pk2(v.x, v.y);
            pk.y = pk2(v.z, v.w);
            *(uint2*)&slab[c][r][cf * 4] = pk;
        }
        __syncthreads();
        #pragma unroll
        for (int it = 0; it < 4; ++it) {
            float v[8];
            #pragma unroll
            for (int t = 0; t < 8; ++t) {
                float val = realA[it] ? __bfloat162float(slab[g * 8 + t][yiA[it]][scA[it]]) : 0.f;
                v[t] = val;
                s0a[it] += val; s1a[it] += val * val;
            }
            xf[it][ks].w[0] = pk2(v[0], v[1]);
            xf[it][ks].w[1] = pk2(v[2], v[3]);
            xf[it][ks].w[2] = pk2(v[4], v[5]);
            xf[it][ks].w[3] = pk2(v[6], v[7]);
        }
        __syncthreads();
    }

    // ---- finish stats, normalize packed raws in place ----
    float mu4[4], rs4[4];
    #pragma unroll
    for (int it = 0; it < 4; ++it) {
        float s0 = s0a[it]; s0 += __shfl_xor(s0, 16); s0 += __shfl_xor(s0, 32);
        float s1 = s1a[it]; s1 += __shfl_xor(s1, 16); s1 += __shfl_xor(s1, 32);
        float mu = s0 * (1.0f / CH);
        mu4[it] = mu;
        rs4[it] = rsqrtf(s1 * (1.0f / CH) - mu * mu + 1e-5f);
    }
    #pragma unroll
    for (int ks = 0; ks < 3; ++ks) {
        float4 gA = *(const float4*)&g1[ks * 32 + g * 8];
        float4 gB = *(const float4*)&g1[ks * 32 + g * 8 + 4];
        float4 bA = *(const float4*)&b1[ks * 32 + g * 8];
        float4 bB = *(const float4*)&b1[ks * 32 + g * 8 + 4];
        float gg[8] = {gA.x, gA.y, gA.z, gA.w, gB.x, gB.y, gB.z, gB.w};
        float bb[8] = {bA.x, bA.y, bA.z, bA.w, bB.x, bB.y, bB.z, bB.w};
        #pragma unroll
        for (int it = 0; it < 4; ++it) {
            #pragma unroll
            for (int w = 0; w < 4; ++w) {
                u32 u = xf[it][ks].w[w];
                float lo = bflo(u), hi = bfhi(u);
                float nlo = realA[it] ? ((lo - mu4[it]) * rs4[it] * gg[2 * w]     + bb[2 * w])     : 0.f;
                float nhi = realA[it] ? ((hi - mu4[it]) * rs4[it] * gg[2 * w + 1] + bb[2 * w + 1]) : 0.f;
                xf[it][ks].w[w] = pk2(nlo, nhi);
            }
        }
    }

    const float scale = 0.17677669529663687f;
    bf16x8 aoB[3][4];

    for (int h = 0; h < 3; ++h) {
        const __hip_bfloat16* qkvTg = wsW + 92160 + h * 9984;

        float qb[2][4], kb[2][4], vb[2][4];
        #pragma unroll
        for (int dt = 0; dt < 2; ++dt)
            #pragma unroll
            for (int r = 0; r < 4; ++r) {
                int d = h * 32 + dt * 16 + g * 4 + r;
                qb[dt][r] = qkv_b[d];
                kb[dt][r] = qkv_b[96 + d];
                vb[dt][r] = qkv_b[192 + d];
            }

        // ---- Q (direct L2 weight frags) ----
        u32 Qpk[2][4][2];
        #pragma unroll
        for (int dt = 0; dt < 2; ++dt) {
            const __hip_bfloat16* wr = qkvTg + (dt * 16 + l15) * 104 + g * 8;
            bf16x8 a0f = *(const bf16x8*)(wr);
            bf16x8 a1f = *(const bf16x8*)(wr + 32);
            bf16x8 a2f = *(const bf16x8*)(wr + 64);
            #pragma unroll
            for (int it = 0; it < 4; ++it) {
                f32x4 c4 = {0.f, 0.f, 0.f, 0.f};
                c4 = __builtin_amdgcn_mfma_f32_16x16x32_bf16(a0f, xf[it][0].v, c4, 0, 0, 0);
                c4 = __builtin_amdgcn_mfma_f32_16x16x32_bf16(a1f, xf[it][1].v, c4, 0, 0, 0);
                c4 = __builtin_amdgcn_mfma_f32_16x16x32_bf16(a2f, xf[it][2].v, c4, 0, 0, 0);
                Qpk[dt][it][0] = pk2(c4[0] + qb[dt][0], c4[1] + qb[dt][1]);
                Qpk[dt][it][1] = pk2(c4[2] + qb[dt][2], c4[3] + qb[dt][3]);
            }
        }
        bf16x8 QB[4];
        #pragma unroll
        for (int it = 0; it < 4; ++it)
            QB[it] = regroup(Qpk[0][it][0], Qpk[0][it][1], Qpk[1][it][0], Qpk[1][it][1], lane);

        // ---- K ----
        u32 Kpk[2][4][2];
        #pragma unroll
        for (int dt = 0; dt < 2; ++dt) {
            const __hip_bfloat16* wr = qkvTg + (32 + dt * 16 + l15) * 104 + g * 8;
            bf16x8 a0f = *(const bf16x8*)(wr);
            bf16x8 a1f = *(const bf16x8*)(wr + 32);
            bf16x8 a2f = *(const bf16x8*)(wr + 64);
            #pragma unroll
            for (int it = 0; it < 4; ++it) {
                f32x4 c4 = {0.f, 0.f, 0.f, 0.f};
                c4 = __builtin_amdgcn_mfma_f32_16x16x32_bf16(a0f, xf[it][0].v, c4, 0, 0, 0);
                c4 = __builtin_amdgcn_mfma_f32_16x16x32_bf16(a1f, xf[it][1].v, c4, 0, 0, 0);
                c4 = __builtin_amdgcn_mfma_f32_16x16x32_bf16(a2f, xf[it][2].v, c4, 0, 0, 0);
                Kpk[dt][it][0] = pk2(c4[0] + kb[dt][0], c4[1] + kb[dt][1]);
                Kpk[dt][it][1] = pk2(c4[2] + kb[dt][2], c4[3] + kb[dt][3]);
            }
        }
        bf16x8 KA[4];
        #pragma unroll
        for (int it = 0; it < 4; ++it)
            KA[it] = regroup(Kpk[0][it][0], Kpk[0][it][1], Kpk[1][it][0], Kpk[1][it][1], lane);

        // ---- V -> vT (per-wave LDS) ----
        #pragma unroll
        for (int dt = 0; dt < 2; ++dt) {
            const __hip_bfloat16* wr = qkvTg + (64 + dt * 16 + l15) * 104 + g * 8;
            bf16x8 a0f = *(const bf16x8*)(wr);
            bf16x8 a1f = *(const bf16x8*)(wr + 32);
            bf16x8 a2f = *(const bf16x8*)(wr + 64);
            #pragma unroll
            for (int it = 0; it < 4; ++it) {
                f32x4 c4 = {0.f, 0.f, 0.f, 0.f};
                c4 = __builtin_amdgcn_mfma_f32_16x16x32_bf16(a0f, xf[it][0].v, c4, 0, 0, 0);
                c4 = __builtin_amdgcn_mfma_f32_16x16x32_bf16(a1f, xf[it][1].v, c4, 0, 0, 0);
                c4 = __builtin_amdgcn_mfma_f32_16x16x32_bf16(a2f, xf[it][2].v, c4, 0, 0, 0);
                #pragma unroll
                for (int r = 0; r < 4; ++r)
                    vT[dt * 16 + g * 4 + r][it * 16 + l15] = __float2bfloat16(c4[r] + vb[dt][r]);
            }
        }
        bf16x8 VBf[2][2];
        #pragma unroll
        for (int dt = 0; dt < 2; ++dt)
            #pragma unroll
            for (int ks = 0; ks < 2; ++ks)
                VBf[dt][ks] = *(const bf16x8*)&vT[dt * 16 + l15][ks * 32 + g * 8];

        // ---- i-tiles: scores + bias (round-10 path) + softmax + PV ----
        #pragma unroll
        for (int it = 0; it < 4; ++it) {
            f32x4 SC[4];
            #pragma unroll
            for (int jt = 0; jt < 4; ++jt) {
                f32x4 z = {0.f, 0.f, 0.f, 0.f};
                SC[jt] = __builtin_amdgcn_mfma_f32_16x16x32_bf16(KA[jt], QB[it], z, 0, 0, 0);
            }
            int i = it * 16 + l15;
            int yi = i / 7, xi = i - yi * 7;
            float p[16];
            float m = -1e30f;
            #pragma unroll
            for (int jt = 0; jt < 4; ++jt)
                #pragma unroll
                for (int r = 0; r < 4; ++r) {
                    int j = jt * 16 + g * 4 + r;
                    int yj = j / 7, xj = j - yj * 7;
                    int rel = (yi - yj + 6) * 13 + (xi - xj + 6);
                    rel = rel < 0 ? 0 : (rel > 168 ? 168 : rel);
                    float s = (j < NTOK) ? (SC[jt][r] * scale + btabL[rel * 3 + h]) : -1e30f;
                    p[jt * 4 + r] = s;
                    m = fmaxf(m, s);
                }
            m = fmaxf(m, __shfl_xor(m, 16));
            m = fmaxf(m, __shfl_xor(m, 32));
            float sum = 0.f;
            #pragma unroll
            for (int q = 0; q < 16; ++q) { float e = __expf(p[q] - m); p[q] = e; sum += e; }
            sum += __shfl_xor(sum, 16);
            sum += __shfl_xor(sum, 32);
            float inv = 1.f / sum;
            u32 Ppk[4][2];
            #pragma unroll
            for (int jt = 0; jt < 4; ++jt) {
                Ppk[jt][0] = pk2(p[jt * 4 + 0] * inv, p[jt * 4 + 1] * inv);
                Ppk[jt][1] = pk2(p[jt * 4 + 2] * inv, p[jt * 4 + 3] * inv);
            }
            bf16x8 PA0 = regroup(Ppk[0][0], Ppk[0][1], Ppk[1][0], Ppk[1][1], lane);
            bf16x8 PA1 = regroup(Ppk[2][0], Ppk[2][1], Ppk[3][0], Ppk[3][1], lane);
            u32 opk[2][2];
            #pragma unroll
            for (int dt = 0; dt < 2; ++dt) {
                f32x4 o = {0.f, 0.f, 0.f, 0.f};
                o = __builtin_amdgcn_mfma_f32_16x16x32_bf16(PA0, VBf[dt][0], o, 0, 0, 0);
                o = __builtin_amdgcn_mfma_f32_16x16x32_bf16(PA1, VBf[dt][1], o, 0, 0, 0);
                opk[dt][0] = pk2(o[0], o[1]);
                opk[dt][1] = pk2(o[2], o[3]);
            }
            aoB[h][it] = regroup(opk[0][0], opk[0][1], opk[1][0], opk[1][1], lane);
        }
    }

    // ---- proj per it-tile (pwT direct from L2): C'[oc][tok] -> per-wave LDS -> coalesced store ----
    const __hip_bfloat16* pwTg = wsW + 81920;
    for (int it = 0; it < 4; ++it) {
        #pragma unroll
        for (int mt = 0; mt < 6; ++mt) {
            const __hip_bfloat16* wr = pwTg + (mt * 16 + l15) * 104 + g * 8;
            f32x4 cp = {0.f, 0.f, 0.f, 0.f};
            #pragma unroll
            for (int ks = 0; ks < 3; ++ks) {
                bf16x8 af = *(const bf16x8*)(wr + ks * 32);
                cp = __builtin_amdgcn_mfma_f32_16x16x32_bf16(af, aoB[ks][it], cp, 0, 0, 0);
            }
            float v0 = cp[0] + pb[mt * 16 + g * 4 + 0];
            float v1 = cp[1] + pb[mt * 16 + g * 4 + 1];
            float v2 = cp[2] + pb[mt * 16 + g * 4 + 2];
            float v3 = cp[3] + pb[mt * 16 + g * 4 + 3];
            prS[l15 * 52 + mt * 8 + g * 2 + 0] = pk2(v0, v1);
            prS[l15 * 52 + mt * 8 + g * 2 + 1] = pk2(v2, v3);
        }
        #pragma unroll
        for (int s = 0; s < 3; ++s) {
            int chunk = lane + 64 * s;
            int row = chunk / 12, q = chunk - row * 12;
            int tok = it * 16 + row;
            if (tok < NTOK) {
                int yi = tok / 7, xi = tok - yi * 7;
                int hh = wh * 7 + yi + SHIFT_; if (hh >= HIMG) hh -= HIMG;
                int wp = ww * 7 + xi + SHIFT_; if (wp >= WIMG) wp -= WIMG;
                float4 val = *(const float4*)((const char*)prS + row * 208 + q * 16);
                *(float4*)(projout + ((size_t)b * HWIMG + hh * WIMG + wp) * 96 + q * 8) = val;
            }
        }
    }
}

// ========== K2 v5 (round-10 proven): pipelined weight staging + f32 coalesced epilogue ==========
#define LDSTG(p0, p1, p2, s) { const float4* _s = wsrc + (s) * 1280; \
    p0 = _s[tid]; p1 = _s[tid + 512]; if (tid < 256) p2 = _s[tid + 1024]; }
#define WRSTG(p0, p1, p2, off) { float4* _d = (float4*)(SB + (off)); \
    _d[tid] = p0; _d[tid + 512] = p1; if (tid < 256) _d[tid + 1024] = p2; }

__global__ __launch_bounds__(512, 4) void mlp2_kernel(
    const float* __restrict__ x, const __hip_bfloat16* __restrict__ projout,
    const float* __restrict__ g2, const float* __restrict__ b2,
    const float* __restrict__ bb1, const float* __restrict__ bb2,
    const __hip_bfloat16* __restrict__ wsW,
    float* __restrict__ out)
{
    const int tid = threadIdx.x;
    const int lane = tid & 63, wv = tid >> 6;
    const int l15 = lane & 15, g = lane >> 4;
    const int b = blockIdx.x / 392;
    const int hw0 = (blockIdx.x % 392) * 128;
    const int tok = wv * 16 + l15;

    __shared__ __align__(16) char SB[50688];
    __shared__ float bb1S[HID];

    __hip_bfloat16 (*xnS)[104] = (__hip_bfloat16(*)[104])SB;
    __hip_bfloat16 (*wT0)[104] = (__hip_bfloat16(*)[104])SB;
    __hip_bfloat16 (*wT1)[104] = (__hip_bfloat16(*)[104])(SB + 20480);
    float* ob = (float*)SB;

    const float4* wsrc = (const float4*)wsW;
    float4 ra0, ra1, ra2, rb0, rb1, rb2;

    LDSTG(ra0, ra1, ra2, 0);

    #pragma unroll
    for (int s = 0; s < 3; ++s) {
        int chunk = tid + 512 * s;
        int row = chunk / 12, q = chunk - row * 12;
        *(float4*)&xnS[row][q * 8] =
            *(const float4*)(projout + ((size_t)b * HWIMG + hw0 + row) * 96 + q * 8);
    }
    for (int idx = tid; idx < HID; idx += 512) bb1S[idx] = bb1[idx];
    __syncthreads();

    float xr[24];
    float s0 = 0.f, s1 = 0.f;
    bf16x8 pf[3];
    #pragma unroll
    for (int ks = 0; ks < 3; ++ks)
        pf[ks] = *(const bf16x8*)&xnS[tok][ks * 32 + g * 8];
    const float* xb = x + (size_t)(b * CH) * HWIMG + hw0 + tok;
    #pragma unroll
    for (int ks = 0; ks < 3; ++ks)
        #pragma unroll
        for (int j = 0; j < 8; ++j) {
            int c = ks * 32 + g * 8 + j;
            float xv = xb[(size_t)c * HWIMG];
            float v = xv + bflo((u32)(u16)pf[ks][j]);
            xr[ks * 8 + j] = v; s0 += v; s1 += v * v;
        }
    s0 += __shfl_xor(s0, 16); s0 += __shfl_xor(s0, 32);
    s1 += __shfl_xor(s1, 16); s1 += __shfl_xor(s1, 32);
    float mu = s0 * (1.0f / CH);
    float rstd = rsqrtf(s1 * (1.0f / CH) - mu * mu + 1e-5f);

    bf16x8 xbf[3];
    #pragma unroll
    for (int ks = 0; ks < 3; ++ks) {
        float nv[8];
        #pragma unroll
        for (int j = 0; j < 8; ++j) {
            int c = ks * 32 + g * 8 + j;
            nv[j] = (xr[ks * 8 + j] - mu) * rstd * g2[c] + b2[c];
        }
        FragU f;
        f.w[0] = pk2(nv[0], nv[1]); f.w[1] = pk2(nv[2], nv[3]);
        f.w[2] = pk2(nv[4], nv[5]); f.w[3] = pk2(nv[6], nv[7]);
        xbf[ks] = f.v;
    }
    __syncthreads();

    WRSTG(ra0, ra1, ra2, 0);
    LDSTG(rb0, rb1, rb2, 1);
    __syncthreads();

    f32x4 acc[6];
    #pragma unroll
    for (int mt = 0; mt < 6; ++mt) {
        #pragma unroll
        for (int r = 0; r < 4; ++r) acc[mt][r] = bb2[mt * 16 + g * 4 + r];
    }

    #pragma unroll
    for (int ch = 0; ch < 4; ++ch) {
        u32 hpk[6][2];
        #pragma unroll
        for (int mt = 0; mt < 6; ++mt) {
            f32x4 f = {0.f, 0.f, 0.f, 0.f};
            #pragma unroll
            for (int ks = 0; ks < 3; ++ks) {
                bf16x8 af = *(const bf16x8*)&wT0[mt * 16 + l15][ks * 32 + g * 8];
                f = __builtin_amdgcn_mfma_f32_16x16x32_bf16(af, xbf[ks], f, 0, 0, 0);
            }
            float gl[4];
            #pragma unroll
            for (int r = 0; r < 4; ++r) {
                float a = f[r] + bb1S[ch * 96 + mt * 16 + g * 4 + r];
                gl[r] = gelu_f(a);
            }
            hpk[mt][0] = pk2(gl[0], gl[1]);
            hpk[mt][1] = pk2(gl[2], gl[3]);
        }
        WRSTG(rb0, rb1, rb2, 20480);
        __syncthreads();
        if (ch < 3) LDSTG(ra0, ra1, ra2, 2 * ch + 2);

        bf16x8 hf[3];
        hf[0] = regroup(hpk[0][0], hpk[0][1], hpk[1][0], hpk[1][1], lane);
        hf[1] = regroup(hpk[2][0], hpk[2][1], hpk[3][0], hpk[3][1], lane);
        hf[2] = regroup(hpk[4][0], hpk[4][1], hpk[5][0], hpk[5][1], lane);
        #pragma unroll
        for (int mt = 0; mt < 6; ++mt) {
            #pragma unroll
            for (int ks = 0; ks < 3; ++ks) {
                bf16x8 af = *(const bf16x8*)&wT1[mt * 16 + l15][ks * 32 + g * 8];
                acc[mt] = __builtin_amdgcn_mfma_f32_16x16x32_bf16(af, hf[ks], acc[mt], 0, 0, 0);
            }
        }
        if (ch < 3) WRSTG(ra0, ra1, ra2, 0);
        __syncthreads();
        if (ch < 3) LDSTG(rb0, rb1, rb2, 2 * ch + 3);
    }

    #pragma unroll
    for (int ks = 0; ks < 3; ++ks)
        #pragma unroll
        for (int j = 0; j < 8; ++j)
            ob[tok * 99 + ks * 32 + g * 8 + j] = xr[ks * 8 + j];
    __syncthreads();
    #pragma unroll
    for (int mt = 0; mt < 6; ++mt)
        #pragma unroll
        for (int r = 0; r < 4; ++r)
            ob[tok * 99 + mt * 16 + g * 4 + r] += acc[mt][r];
    __syncthreads();
    #pragma unroll
    for (int k = 0; k < 24; ++k) {
        int idx = tid + 512 * k;
        int c = idx >> 7, t = idx & 127;
        out[(size_t)(b * CH + c) * HWIMG + hw0 + t] = ob[t * 99 + c];
    }
}

// ================= FALLBACK (minimal, correct): used only if ws too small =================
__global__ __launch_bounds__(256) void attn_fb_kernel(
    const float* __restrict__ x,
    const float* __restrict__ g1, const float* __restrict__ b1,
    const float* __restrict__ qkv_w, const float* __restrict__ qkv_b,
    const float* __restrict__ proj_w, const float* __restrict__ proj_b,
    const float* __restrict__ btab,
    float* __restrict__ out)
{
    const int tid = threadIdx.x;
    const int wid = blockIdx.x;
    const int b  = wid >> 10;
    const int wh = (wid >> 5) & 31;
    const int ww = wid & 31;

    __shared__ float ao[NTOK][CH + 1];
    __shared__ __hip_bfloat16 xnb[NTOK][CH + 2];
    __shared__ float qs[NTOK][33], ks_[NTOK][33], vs[NTOK][33];
    __shared__ float ss[NTOK][NTOK + 1];
    __shared__ float mu[NTOK], rs[NTOK];

    float xreg[19];

    for (int idx = tid, k = 0; idx < NTOK * CH; idx += 256, ++k) {
        int c = idx / NTOK, n = idx % NTOK;
        int i = n / WSZ, j = n % WSZ;
        int h = wh * WSZ + i + SHIFT_; if (h >= HIMG) h -= HIMG;
        int w = ww * WSZ + j + SHIFT_; if (w >= WIMG) w -= WIMG;
        float v = x[((size_t)(b * CH + c) * HIMG + h) * WIMG + w];
        ao[n][c] = v; xreg[k] = v;
    }
    __syncthreads();
    if (tid < NTOK) {
        float s0 = 0.f, s1 = 0.f;
        for (int c = 0; c < CH; ++c) { float v = ao[tid][c]; s0 += v; s1 += v * v; }
        float m = s0 / CH;
        mu[tid] = m; rs[tid] = rsqrtf(s1 / CH - m * m + 1e-5f);
    }
    __syncthreads();
    for (int idx = tid; idx < NTOK * CH; idx += 256) {
        int c = idx / NTOK, n = idx % NTOK;
        xnb[n][c] = __float2bfloat16((ao[n][c] - mu[n]) * rs[n] * g1[c] + b1[c]);
    }
    __syncthreads();
    const float scale = 0.17677669529663687f;
    for (int hh = 0; hh < 3; ++hh) {
        for (int idx = tid; idx < 3 * 32 * NTOK; idx += 256) {
            int col = idx / NTOK, n = idx % NTOK;
            int which = col >> 5, d = col & 31;
            int gc = which * CH + hh * 32 + d;
            float acc = qkv_b[gc];
            for (int c = 0; c < CH; ++c)
                acc += __bfloat162float(xnb[n][c]) * qkv_w[c * 288 + gc];
            if (which == 0) qs[n][d] = acc;
            else if (which == 1) ks_[n][d] = acc;
            else vs[n][d] = acc;
        }
        __syncthreads();
        for (int idx = tid; idx < NTOK * NTOK; idx += 256) {
            int i = idx / NTOK, j = idx % NTOK;
            float acc = 0.f;
            for (int d = 0; d < 32; ++d) acc += qs[i][d] * ks_[j][d];
            int yi = i / WSZ, xi = i % WSZ, yj = j / WSZ, xj = j % WSZ;
            int rel = (yi - yj + 6) * 13 + (xi - xj + 6);
            ss[i][j] = acc * scale + btab[rel * 3 + hh];
        }
        __syncthreads();
        if (tid < NTOK) {
            float m = -1e30f;
            for (int j = 0; j < NTOK; ++j) m = fmaxf(m, ss[tid][j]);
            float sum = 0.f;
            for (int j = 0; j < NTOK; ++j) { float e = __expf(ss[tid][j] - m); ss[tid][j] = e; sum += e; }
            float inv = 1.f / sum;
            for (int j = 0; j < NTOK; ++j) ss[tid][j] *= inv;
        }
        __syncthreads();
        for (int idx = tid; idx < NTOK * 32; idx += 256) {
            int n = idx / 32, d = idx % 32;
            float acc = 0.f;
            for (int j = 0; j < NTOK; ++j) acc += ss[n][j] * vs[j][d];
            ao[n][hh * 32 + d] = acc;
        }
        __syncthreads();
    }
    for (int idx = tid, k = 0; idx < NTOK * CH; idx += 256, ++k) {
        int oc = idx / NTOK, n = idx % NTOK;
        int i = n / WSZ, j = n % WSZ;
        int h = wh * WSZ + i + SHIFT_; if (h >= HIMG) h -= HIMG;
        int w = ww * WSZ + j + SHIFT_; if (w >= WIMG) w -= WIMG;
        float acc = proj_b[oc];
        for (int cc = 0; cc < CH; ++cc) acc += ao[n][cc] * proj_w[cc * CH + oc];
        out[((size_t)(b * CH + oc) * HIMG + h) * WIMG + w] = xreg[k] + acc;
    }
}

__global__ __launch_bounds__(256) void mlp_fb_kernel(
    const float* __restrict__ g2, const float* __restrict__ b2,
    const float* __restrict__ w1, const float* __restrict__ bb1,
    const float* __restrict__ w2, const float* __restrict__ bb2,
    float* __restrict__ io)
{
    const int tid = threadIdx.x;
    const int b = blockIdx.x / 784;
    const int hw0 = (blockIdx.x % 784) * 64;

    __shared__ float xt[CH][64];
    __shared__ __hip_bfloat16 xn2[CH][66];
    __shared__ float hbuf[64][65];
    __shared__ float mu2[64], rs2[64];

    for (int idx = tid; idx < CH * 64; idx += 256) {
        int c = idx / 64, t = idx % 64;
        xt[c][t] = io[((size_t)(b * CH + c)) * HWIMG + hw0 + t];
    }
    __syncthreads();
    if (tid < 64) {
        float s0 = 0.f, s1 = 0.f;
        for (int c = 0; c < CH; ++c) { float v = xt[c][tid]; s0 += v; s1 += v * v; }
        float m = s0 / CH;
        mu2[tid] = m; rs2[tid] = rsqrtf(s1 / CH - m * m + 1e-5f);
    }
    __syncthreads();
    for (int idx = tid; idx < CH * 64; idx += 256) {
        int c = idx / 64, t = idx % 64;
        xn2[c][t] = __float2bfloat16((xt[c][t] - mu2[t]) * rs2[t] * g2[c] + b2[c]);
    }
    __syncthreads();
    const int tt = tid & 63, oc0 = tid >> 6;
    float acc[24];
    #pragma unroll
    for (int k = 0; k < 24; ++k) acc[k] = bb2[oc0 + 4 * k];
    for (int kc = 0; kc < HID; kc += 64) {
        for (int idx = tid; idx < 64 * 64; idx += 256) {
            int kk = idx / 64, t = idx % 64;
            float a = bb1[kc + kk];
            for (int c = 0; c < CH; ++c)
                a += __bfloat162float(xn2[c][t]) * w1[c * HID + kc + kk];
            hbuf[t][kk] = gelu_f(a);
        }
        __syncthreads();
        for (int kk = 0; kk < 64; ++kk) {
            float hv = hbuf[tt][kk];
            const float* wrow = &w2[(size_t)(kc + kk) * CH + oc0];
            #pragma unroll
            for (int k = 0; k < 24; ++k) acc[k] += hv * wrow[4 * k];
        }
        __syncthreads();
    }
    #pragma unroll
    for (int k = 0; k < 24; ++k) {
        int oc = oc0 + 4 * k;
        io[((size_t)(b * CH + oc)) * HWIMG + hw0 + tt] = xt[oc][tt] + acc[k];
    }
}

extern "C" void kernel_launch(void* const* d_in, const int* in_sizes, int n_in,
                              void* d_out, int out_size, void* d_ws, size_t ws_size,
                              hipStream_t stream) {
    const float* x    = (const float*)d_in[0];
    const float* n1g  = (const float*)d_in[1];
    const float* n1b  = (const float*)d_in[2];
    const float* qkvw = (const float*)d_in[3];
    const float* qkvb = (const float*)d_in[4];
    const float* pw   = (const float*)d_in[5];
    const float* pbv  = (const float*)d_in[6];
    const float* bt   = (const float*)d_in[7];
    const float* n2g  = (const float*)d_in[8];
    const float* n2b  = (const float*)d_in[9];
    const float* f1w  = (const float*)d_in[10];
    const float* f1b  = (const float*)d_in[11];
    const float* f2w  = (const float*)d_in[12];
    const float* f2b  = (const float*)d_in[13];
    float* out = (float*)d_out;

    const size_t FULL_NEED = 262144ull + 77070336ull;
    if (ws_size >= FULL_NEED) {
        __hip_bfloat16* wsW = (__hip_bfloat16*)d_ws;
        __hip_bfloat16* projout = (__hip_bfloat16*)((char*)d_ws + 262144);
        prep_kernel<<<477, 256, 0, stream>>>(f1w, f2w, pw, qkvw, wsW, 122112);
        attn2_kernel<<<2048, 256, 0, stream>>>(x, n1g, n1b, wsW, qkvb, pbv, bt, projout);
        mlp2_kernel<<<3136, 512, 0, stream>>>(x, projout, n2g, n2b, f1b, f2b, wsW, out);
    } else {
        attn_fb_kernel<<<8192, 256, 0, stream>>>(x, n1g, n1b, qkvw, qkvb, pw, pbv, bt, out);
        mlp_fb_kernel<<<8 * 784, 256, 0, stream>>>(n2g, n2b, f1w, f1b, f2w, f2b, out);
    }
}

// Round 14
// 406.862 us; speedup vs baseline: 1.1956x; 1.1956x over previous
//
#include <hip/hip_runtime.h>
#include <hip/hip_bf16.h>
#include <math.h>

#define WSZ 7
#define NTOK 49
#define CH 96
#define HIMG 224
#define WIMG 224
#define HWIMG (224*224)
#define SHIFT_ 3
#define HID 384

typedef __attribute__((ext_vector_type(8))) short bf16x8;
typedef __attribute__((ext_vector_type(4))) float f32x4;
typedef unsigned int u32;
typedef unsigned short u16;

__device__ __forceinline__ u32 pk2(float a, float b) {
    u16 ua = __builtin_bit_cast(u16, __float2bfloat16(a));
    u16 ub = __builtin_bit_cast(u16, __float2bfloat16(b));
    return (u32)ua | ((u32)ub << 16);
}
__device__ __forceinline__ float bflo(u32 u) { return __builtin_bit_cast(float, u << 16); }

union FragU { u32 w[4]; bf16x8 v; };

// regroup: C'-frags of two 16-row tiles (rows g*4+r, cols l15) -> A/B-frag
__device__ __forceinline__ bf16x8 regroup(u32 t0w0, u32 t0w1, u32 t1w0, u32 t1w1, int lane) {
    int sl0 = (lane & 15) + ((lane & 16) << 1);
    int sl1 = sl0 + 16;
    u32 x0 = (u32)__shfl((int)t0w0, sl0);
    u32 y0 = (u32)__shfl((int)t1w0, sl0);
    u32 x1 = (u32)__shfl((int)t0w1, sl0);
    u32 y1 = (u32)__shfl((int)t1w1, sl0);
    u32 x2 = (u32)__shfl((int)t0w0, sl1);
    u32 y2 = (u32)__shfl((int)t1w0, sl1);
    u32 x3 = (u32)__shfl((int)t0w1, sl1);
    u32 y3 = (u32)__shfl((int)t1w1, sl1);
    bool lo = lane < 32;
    FragU f;
    f.w[0] = lo ? x0 : y0;
    f.w[1] = lo ? x1 : y1;
    f.w[2] = lo ? x2 : y2;
    f.w[3] = lo ? x3 : y3;
    return f.v;
}

// tanh-approx GELU as x*sigmoid(2s): no division.
__device__ __forceinline__ float gelu_f(float x) {
    float x2 = x * x;
    float t  = x * (1.5957691216057308f + 0.07135481283587191f * x2);
    float e  = __expf(t);
    float r  = __builtin_amdgcn_rcpf(e + 1.0f);
    return x - x * r;
}

// ---------- prep (round-7 proven) ----------
__global__ __launch_bounds__(256) void prep_kernel(
    const float* __restrict__ w1, const float* __restrict__ w2,
    const float* __restrict__ pw, const float* __restrict__ qw,
    __hip_bfloat16* __restrict__ ws, int n)
{
    int i = blockIdx.x * 256 + threadIdx.x;
    if (i >= n) return;
    float val = 0.f;
    if (i < 81920) {
        int ch = i / 20480, r = i - ch * 20480;
        int half = r / 10240;
        int rr = r - half * 10240;
        if (rr < 9984) {
            int row = rr / 104, col = rr - row * 104;
            if (col < 96)
                val = (half == 0) ? w1[col * HID + ch * 96 + row]
                                  : w2[(size_t)(ch * 96 + col) * CH + row];
        }
    } else if (i < 92160) {
        int r = i - 81920;
        if (r < 9984) {
            int row = r / 104, col = r - row * 104;
            if (col < 96) val = pw[col * CH + row];
        }
    } else {
        int j = i - 92160;
        int hh = j / 9984, rr = j - hh * 9984;
        int dp = rr / 104, c = rr - dp * 104;
        if (c < 96) {
            int colW = (dp < 32) ? (hh * 32 + dp)
                     : (dp < 64) ? (96 + hh * 32 + dp - 32)
                                 : (192 + hh * 32 + dp - 64);
            val = qw[c * 288 + colW];
        }
    }
    ws[i] = __float2bfloat16(val);
}

// ========== K1 (round-10 proven structure + s_setprio around MFMA clusters) ==========
__global__ __launch_bounds__(256) void attn2_kernel(
    const float* __restrict__ x,
    const float* __restrict__ g1, const float* __restrict__ b1,
    const __hip_bfloat16* __restrict__ wsW,
    const float* __restrict__ qkv_b, const float* __restrict__ pb,
    const float* __restrict__ btab,
    __hip_bfloat16* __restrict__ projout)
{
    const int tid  = threadIdx.x;
    const int lane = tid & 63;
    const int wv   = tid >> 6;
    const int l15  = lane & 15;
    const int g    = lane >> 4;
    const int bi   = blockIdx.x;
    const int b    = bi >> 8;            // 256 blocks per image
    const int wh   = (bi >> 3) & 31;
    const int ww0  = (bi & 7) * 4;       // first of 4 windows
    const int ww   = ww0 + wv;

    __shared__ float btabL[507];
    __shared__ __align__(16) char uniA[43008];   // strip xsb[96][7][32] bf16 | later per-wave 4x4608

    __hip_bfloat16 (*xsb)[7][32] = (__hip_bfloat16(*)[7][32])uniA;
    __hip_bfloat16 (*vT)[72] = (__hip_bfloat16(*)[72])(uniA + wv * 4608);
    u32* prS = (u32*)(uniA + wv * 4608);

    for (int idx = tid; idx < 507; idx += 256) btabL[idx] = btab[idx];

    // ---- cooperative stage: shifted strip rows [wh*7+3 .. +9], cols aligned 32 ----
    const int colBase = ww0 * 7 + 3;
    const int cA  = colBase & ~3;
    const int cb4 = cA >> 2;
    const int a0  = colBase & 3;
    #pragma unroll
    for (int k = 0; k < 21; ++k) {       // 96*7*8 float4 / 256 threads
        int idx = tid + 256 * k;
        int c = idx / 56, rem = idx - c * 56;
        int r = rem >> 3, cf = rem & 7;
        int gr = wh * 7 + 3 + r; if (gr >= HIMG) gr -= HIMG;
        int g4 = cb4 + cf; if (g4 >= 56) g4 -= 56;
        float4 v = *(const float4*)(x + ((size_t)(b * CH + c) * HIMG + gr) * WIMG + g4 * 4);
        uint2 pk;
        pk.x = pk2(v.x, v.y);
        pk.y = pk2(v.z, v.w);
        *(uint2*)&xsb[c][r][cf * 4] = pk;
    }
    __syncthreads();

    // ---- LN1: xn B-fragments fully in registers (reads from LDS strip) ----
    bf16x8 xB[4][3];
    #pragma unroll
    for (int it = 0; it < 4; ++it) {
        int i = it * 16 + l15;
        bool real = i < NTOK;
        int yi = i / 7, xi = i - yi * 7;
        int sc = a0 + wv * 7 + xi;
        float raw[24];
        float s0 = 0.f, s1 = 0.f;
        #pragma unroll
        for (int ks = 0; ks < 3; ++ks)
            #pragma unroll
            for (int t = 0; t < 8; ++t) {
                int c = ks * 32 + g * 8 + t;
                float v = real ? __bfloat162float(xsb[c][yi][sc]) : 0.f;
                raw[ks * 8 + t] = v; s0 += v; s1 += v * v;
            }
        s0 += __shfl_xor(s0, 16); s0 += __shfl_xor(s0, 32);
        s1 += __shfl_xor(s1, 16); s1 += __shfl_xor(s1, 32);
        float mu = s0 * (1.0f / CH);
        float rstd = rsqrtf(s1 * (1.0f / CH) - mu * mu + 1e-5f);
        #pragma unroll
        for (int ks = 0; ks < 3; ++ks)
            #pragma unroll
            for (int t = 0; t < 8; ++t) {
                int c = ks * 32 + g * 8 + t;
                float xv = real ? ((raw[ks * 8 + t] - mu) * rstd * g1[c] + b1[c]) : 0.f;
                xB[it][ks][t] = (short)__builtin_bit_cast(u16, __float2bfloat16(xv));
            }
    }
    __syncthreads();   // strip dead; per-wave scratch (vT/prS) may now overwrite uniA

    const float scale = 0.17677669529663687f;
    bf16x8 aoB[3][4];

    for (int h = 0; h < 3; ++h) {
        const __hip_bfloat16* qkvTg = wsW + 92160 + h * 9984;

        float qb[2][4], kb[2][4], vb[2][4];
        #pragma unroll
        for (int dt = 0; dt < 2; ++dt)
            #pragma unroll
            for (int r = 0; r < 4; ++r) {
                int d = h * 32 + dt * 16 + g * 4 + r;
                qb[dt][r] = qkv_b[d];
                kb[dt][r] = qkv_b[96 + d];
                vb[dt][r] = qkv_b[192 + d];
            }

        // ---- Q (direct L2 weight frags) ----
        __builtin_amdgcn_s_setprio(1);
        u32 Qpk[2][4][2];
        #pragma unroll
        for (int dt = 0; dt < 2; ++dt) {
            const __hip_bfloat16* wr = qkvTg + (dt * 16 + l15) * 104 + g * 8;
            bf16x8 a0f = *(const bf16x8*)(wr);
            bf16x8 a1f = *(const bf16x8*)(wr + 32);
            bf16x8 a2f = *(const bf16x8*)(wr + 64);
            #pragma unroll
            for (int it = 0; it < 4; ++it) {
                f32x4 c4 = {0.f, 0.f, 0.f, 0.f};
                c4 = __builtin_amdgcn_mfma_f32_16x16x32_bf16(a0f, xB[it][0], c4, 0, 0, 0);
                c4 = __builtin_amdgcn_mfma_f32_16x16x32_bf16(a1f, xB[it][1], c4, 0, 0, 0);
                c4 = __builtin_amdgcn_mfma_f32_16x16x32_bf16(a2f, xB[it][2], c4, 0, 0, 0);
                Qpk[dt][it][0] = pk2(c4[0] + qb[dt][0], c4[1] + qb[dt][1]);
                Qpk[dt][it][1] = pk2(c4[2] + qb[dt][2], c4[3] + qb[dt][3]);
            }
        }
        bf16x8 QB[4];
        #pragma unroll
        for (int it = 0; it < 4; ++it)
            QB[it] = regroup(Qpk[0][it][0], Qpk[0][it][1], Qpk[1][it][0], Qpk[1][it][1], lane);

        // ---- K ----
        u32 Kpk[2][4][2];
        #pragma unroll
        for (int dt = 0; dt < 2; ++dt) {
            const __hip_bfloat16* wr = qkvTg + (32 + dt * 16 + l15) * 104 + g * 8;
            bf16x8 a0f = *(const bf16x8*)(wr);
            bf16x8 a1f = *(const bf16x8*)(wr + 32);
            bf16x8 a2f = *(const bf16x8*)(wr + 64);
            #pragma unroll
            for (int it = 0; it < 4; ++it) {
                f32x4 c4 = {0.f, 0.f, 0.f, 0.f};
                c4 = __builtin_amdgcn_mfma_f32_16x16x32_bf16(a0f, xB[it][0], c4, 0, 0, 0);
                c4 = __builtin_amdgcn_mfma_f32_16x16x32_bf16(a1f, xB[it][1], c4, 0, 0, 0);
                c4 = __builtin_amdgcn_mfma_f32_16x16x32_bf16(a2f, xB[it][2], c4, 0, 0, 0);
                Kpk[dt][it][0] = pk2(c4[0] + kb[dt][0], c4[1] + kb[dt][1]);
                Kpk[dt][it][1] = pk2(c4[2] + kb[dt][2], c4[3] + kb[dt][3]);
            }
        }
        bf16x8 KA[4];
        #pragma unroll
        for (int it = 0; it < 4; ++it)
            KA[it] = regroup(Kpk[0][it][0], Kpk[0][it][1], Kpk[1][it][0], Kpk[1][it][1], lane);

        // ---- V -> vT (per-wave LDS) ----
        #pragma unroll
        for (int dt = 0; dt < 2; ++dt) {
            const __hip_bfloat16* wr = qkvTg + (64 + dt * 16 + l15) * 104 + g * 8;
            bf16x8 a0f = *(const bf16x8*)(wr);
            bf16x8 a1f = *(const bf16x8*)(wr + 32);
            bf16x8 a2f = *(const bf16x8*)(wr + 64);
            #pragma unroll
            for (int it = 0; it < 4; ++it) {
                f32x4 c4 = {0.f, 0.f, 0.f, 0.f};
                c4 = __builtin_amdgcn_mfma_f32_16x16x32_bf16(a0f, xB[it][0], c4, 0, 0, 0);
                c4 = __builtin_amdgcn_mfma_f32_16x16x32_bf16(a1f, xB[it][1], c4, 0, 0, 0);
                c4 = __builtin_amdgcn_mfma_f32_16x16x32_bf16(a2f, xB[it][2], c4, 0, 0, 0);
                #pragma unroll
                for (int r = 0; r < 4; ++r)
                    vT[dt * 16 + g * 4 + r][it * 16 + l15] = __float2bfloat16(c4[r] + vb[dt][r]);
            }
        }
        __builtin_amdgcn_s_setprio(0);
        bf16x8 VBf[2][2];
        #pragma unroll
        for (int dt = 0; dt < 2; ++dt)
            #pragma unroll
            for (int ks = 0; ks < 2; ++ks)
                VBf[dt][ks] = *(const bf16x8*)&vT[dt * 16 + l15][ks * 32 + g * 8];

        // ---- i-tiles: scores + softmax + PV -> aoB frags ----
        #pragma unroll
        for (int it = 0; it < 4; ++it) {
            __builtin_amdgcn_s_setprio(1);
            f32x4 SC[4];
            #pragma unroll
            for (int jt = 0; jt < 4; ++jt) {
                f32x4 z = {0.f, 0.f, 0.f, 0.f};
                SC[jt] = __builtin_amdgcn_mfma_f32_16x16x32_bf16(KA[jt], QB[it], z, 0, 0, 0);
            }
            __builtin_amdgcn_s_setprio(0);
            int i = it * 16 + l15;
            int yi = i / 7, xi = i - yi * 7;
            float p[16];
            float m = -1e30f;
            #pragma unroll
            for (int jt = 0; jt < 4; ++jt)
                #pragma unroll
                for (int r = 0; r < 4; ++r) {
                    int j = jt * 16 + g * 4 + r;
                    int yj = j / 7, xj = j - yj * 7;
                    int rel = (yi - yj + 6) * 13 + (xi - xj + 6);
                    rel = rel < 0 ? 0 : (rel > 168 ? 168 : rel);
                    float s = (j < NTOK) ? (SC[jt][r] * scale + btabL[rel * 3 + h]) : -1e30f;
                    p[jt * 4 + r] = s;
                    m = fmaxf(m, s);
                }
            m = fmaxf(m, __shfl_xor(m, 16));
            m = fmaxf(m, __shfl_xor(m, 32));
            float sum = 0.f;
            #pragma unroll
            for (int q = 0; q < 16; ++q) { float e = __expf(p[q] - m); p[q] = e; sum += e; }
            sum += __shfl_xor(sum, 16);
            sum += __shfl_xor(sum, 32);
            float inv = 1.f / sum;
            u32 Ppk[4][2];
            #pragma unroll
            for (int jt = 0; jt < 4; ++jt) {
                Ppk[jt][0] = pk2(p[jt * 4 + 0] * inv, p[jt * 4 + 1] * inv);
                Ppk[jt][1] = pk2(p[jt * 4 + 2] * inv, p[jt * 4 + 3] * inv);
            }
            bf16x8 PA0 = regroup(Ppk[0][0], Ppk[0][1], Ppk[1][0], Ppk[1][1], lane);
            bf16x8 PA1 = regroup(Ppk[2][0], Ppk[2][1], Ppk[3][0], Ppk[3][1], lane);
            u32 opk[2][2];
            __builtin_amdgcn_s_setprio(1);
            #pragma unroll
            for (int dt = 0; dt < 2; ++dt) {
                f32x4 o = {0.f, 0.f, 0.f, 0.f};
                o = __builtin_amdgcn_mfma_f32_16x16x32_bf16(PA0, VBf[dt][0], o, 0, 0, 0);
                o = __builtin_amdgcn_mfma_f32_16x16x32_bf16(PA1, VBf[dt][1], o, 0, 0, 0);
                opk[dt][0] = pk2(o[0], o[1]);
                opk[dt][1] = pk2(o[2], o[3]);
            }
            __builtin_amdgcn_s_setprio(0);
            aoB[h][it] = regroup(opk[0][0], opk[0][1], opk[1][0], opk[1][1], lane);
        }
    }

    // ---- proj per it-tile (pwT direct from L2): C'[oc][tok] -> per-wave LDS -> coalesced store ----
    const __hip_bfloat16* pwTg = wsW + 81920;
    for (int it = 0; it < 4; ++it) {
        __builtin_amdgcn_s_setprio(1);
        #pragma unroll
        for (int mt = 0; mt < 6; ++mt) {
            const __hip_bfloat16* wr = pwTg + (mt * 16 + l15) * 104 + g * 8;
            f32x4 cp = {0.f, 0.f, 0.f, 0.f};
            #pragma unroll
            for (int ks = 0; ks < 3; ++ks) {
                bf16x8 af = *(const bf16x8*)(wr + ks * 32);
                cp = __builtin_amdgcn_mfma_f32_16x16x32_bf16(af, aoB[ks][it], cp, 0, 0, 0);
            }
            float v0 = cp[0] + pb[mt * 16 + g * 4 + 0];
            float v1 = cp[1] + pb[mt * 16 + g * 4 + 1];
            float v2 = cp[2] + pb[mt * 16 + g * 4 + 2];
            float v3 = cp[3] + pb[mt * 16 + g * 4 + 3];
            prS[l15 * 52 + mt * 8 + g * 2 + 0] = pk2(v0, v1);
            prS[l15 * 52 + mt * 8 + g * 2 + 1] = pk2(v2, v3);
        }
        __builtin_amdgcn_s_setprio(0);
        #pragma unroll
        for (int s = 0; s < 3; ++s) {
            int chunk = lane + 64 * s;
            int row = chunk / 12, q = chunk - row * 12;
            int tok = it * 16 + row;
            if (tok < NTOK) {
                int yi = tok / 7, xi = tok - yi * 7;
                int hh = wh * 7 + yi + SHIFT_; if (hh >= HIMG) hh -= HIMG;
                int wp = ww * 7 + xi + SHIFT_; if (wp >= WIMG) wp -= WIMG;
                float4 val = *(const float4*)((const char*)prS + row * 208 + q * 16);
                *(float4*)(projout + ((size_t)b * HWIMG + hh * WIMG + wp) * 96 + q * 8) = val;
            }
        }
    }
}

// ========== K2 v5 (round-10 proven): pipelined weight staging + f32 coalesced epilogue ==========
#define LDSTG(p0, p1, p2, s) { const float4* _s = wsrc + (s) * 1280; \
    p0 = _s[tid]; p1 = _s[tid + 512]; if (tid < 256) p2 = _s[tid + 1024]; }
#define WRSTG(p0, p1, p2, off) { float4* _d = (float4*)(SB + (off)); \
    _d[tid] = p0; _d[tid + 512] = p1; if (tid < 256) _d[tid + 1024] = p2; }

__global__ __launch_bounds__(512, 4) void mlp2_kernel(
    const float* __restrict__ x, const __hip_bfloat16* __restrict__ projout,
    const float* __restrict__ g2, const float* __restrict__ b2,
    const float* __restrict__ bb1, const float* __restrict__ bb2,
    const __hip_bfloat16* __restrict__ wsW,
    float* __restrict__ out)
{
    const int tid = threadIdx.x;
    const int lane = tid & 63, wv = tid >> 6;
    const int l15 = lane & 15, g = lane >> 4;
    const int b = blockIdx.x / 392;
    const int hw0 = (blockIdx.x % 392) * 128;
    const int tok = wv * 16 + l15;

    __shared__ __align__(16) char SB[50688];
    __shared__ float bb1S[HID];

    __hip_bfloat16 (*xnS)[104] = (__hip_bfloat16(*)[104])SB;
    __hip_bfloat16 (*wT0)[104] = (__hip_bfloat16(*)[104])SB;
    __hip_bfloat16 (*wT1)[104] = (__hip_bfloat16(*)[104])(SB + 20480);
    float* ob = (float*)SB;

    const float4* wsrc = (const float4*)wsW;
    float4 ra0, ra1, ra2, rb0, rb1, rb2;

    LDSTG(ra0, ra1, ra2, 0);

    #pragma unroll
    for (int s = 0; s < 3; ++s) {
        int chunk = tid + 512 * s;
        int row = chunk / 12, q = chunk - row * 12;
        *(float4*)&xnS[row][q * 8] =
            *(const float4*)(projout + ((size_t)b * HWIMG + hw0 + row) * 96 + q * 8);
    }
    for (int idx = tid; idx < HID; idx += 512) bb1S[idx] = bb1[idx];
    __syncthreads();

    float xr[24];
    float s0 = 0.f, s1 = 0.f;
    bf16x8 pf[3];
    #pragma unroll
    for (int ks = 0; ks < 3; ++ks)
        pf[ks] = *(const bf16x8*)&xnS[tok][ks * 32 + g * 8];
    const float* xb = x + (size_t)(b * CH) * HWIMG + hw0 + tok;
    #pragma unroll
    for (int ks = 0; ks < 3; ++ks)
        #pragma unroll
        for (int j = 0; j < 8; ++j) {
            int c = ks * 32 + g * 8 + j;
            float xv = xb[(size_t)c * HWIMG];
            float v = xv + bflo((u32)(u16)pf[ks][j]);
            xr[ks * 8 + j] = v; s0 += v; s1 += v * v;
        }
    s0 += __shfl_xor(s0, 16); s0 += __shfl_xor(s0, 32);
    s1 += __shfl_xor(s1, 16); s1 += __shfl_xor(s1, 32);
    float mu = s0 * (1.0f / CH);
    float rstd = rsqrtf(s1 * (1.0f / CH) - mu * mu + 1e-5f);

    bf16x8 xbf[3];
    #pragma unroll
    for (int ks = 0; ks < 3; ++ks) {
        float nv[8];
        #pragma unroll
        for (int j = 0; j < 8; ++j) {
            int c = ks * 32 + g * 8 + j;
            nv[j] = (xr[ks * 8 + j] - mu) * rstd * g2[c] + b2[c];
        }
        FragU f;
        f.w[0] = pk2(nv[0], nv[1]); f.w[1] = pk2(nv[2], nv[3]);
        f.w[2] = pk2(nv[4], nv[5]); f.w[3] = pk2(nv[6], nv[7]);
        xbf[ks] = f.v;
    }
    __syncthreads();

    WRSTG(ra0, ra1, ra2, 0);
    LDSTG(rb0, rb1, rb2, 1);
    __syncthreads();

    f32x4 acc[6];
    #pragma unroll
    for (int mt = 0; mt < 6; ++mt) {
        #pragma unroll
        for (int r = 0; r < 4; ++r) acc[mt][r] = bb2[mt * 16 + g * 4 + r];
    }

    #pragma unroll
    for (int ch = 0; ch < 4; ++ch) {
        u32 hpk[6][2];
        #pragma unroll
        for (int mt = 0; mt < 6; ++mt) {
            f32x4 f = {0.f, 0.f, 0.f, 0.f};
            #pragma unroll
            for (int ks = 0; ks < 3; ++ks) {
                bf16x8 af = *(const bf16x8*)&wT0[mt * 16 + l15][ks * 32 + g * 8];
                f = __builtin_amdgcn_mfma_f32_16x16x32_bf16(af, xbf[ks], f, 0, 0, 0);
            }
            float gl[4];
            #pragma unroll
            for (int r = 0; r < 4; ++r) {
                float a = f[r] + bb1S[ch * 96 + mt * 16 + g * 4 + r];
                gl[r] = gelu_f(a);
            }
            hpk[mt][0] = pk2(gl[0], gl[1]);
            hpk[mt][1] = pk2(gl[2], gl[3]);
        }
        WRSTG(rb0, rb1, rb2, 20480);
        __syncthreads();
        if (ch < 3) LDSTG(ra0, ra1, ra2, 2 * ch + 2);

        bf16x8 hf[3];
        hf[0] = regroup(hpk[0][0], hpk[0][1], hpk[1][0], hpk[1][1], lane);
        hf[1] = regroup(hpk[2][0], hpk[2][1], hpk[3][0], hpk[3][1], lane);
        hf[2] = regroup(hpk[4][0], hpk[4][1], hpk[5][0], hpk[5][1], lane);
        #pragma unroll
        for (int mt = 0; mt < 6; ++mt) {
            #pragma unroll
            for (int ks = 0; ks < 3; ++ks) {
                bf16x8 af = *(const bf16x8*)&wT1[mt * 16 + l15][ks * 32 + g * 8];
                acc[mt] = __builtin_amdgcn_mfma_f32_16x16x32_bf16(af, hf[ks], acc[mt], 0, 0, 0);
            }
        }
        if (ch < 3) WRSTG(ra0, ra1, ra2, 0);
        __syncthreads();
        if (ch < 3) LDSTG(rb0, rb1, rb2, 2 * ch + 3);
    }

    #pragma unroll
    for (int ks = 0; ks < 3; ++ks)
        #pragma unroll
        for (int j = 0; j < 8; ++j)
            ob[tok * 99 + ks * 32 + g * 8 + j] = xr[ks * 8 + j];
    __syncthreads();
    #pragma unroll
    for (int mt = 0; mt < 6; ++mt)
        #pragma unroll
        for (int r = 0; r < 4; ++r)
            ob[tok * 99 + mt * 16 + g * 4 + r] += acc[mt][r];
    __syncthreads();
    #pragma unroll
    for (int k = 0; k < 24; ++k) {
        int idx = tid + 512 * k;
        int c = idx >> 7, t = idx & 127;
        out[(size_t)(b * CH + c) * HWIMG + hw0 + t] = ob[t * 99 + c];
    }
}

// ================= FALLBACK (minimal, correct): used only if ws too small =================
__global__ __launch_bounds__(256) void attn_fb_kernel(
    const float* __restrict__ x,
    const float* __restrict__ g1, const float* __restrict__ b1,
    const float* __restrict__ qkv_w, const float* __restrict__ qkv_b,
    const float* __restrict__ proj_w, const float* __restrict__ proj_b,
    const float* __restrict__ btab,
    float* __restrict__ out)
{
    const int tid = threadIdx.x;
    const int wid = blockIdx.x;
    const int b  = wid >> 10;
    const int wh = (wid >> 5) & 31;
    const int ww = wid & 31;

    __shared__ float ao[NTOK][CH + 1];
    __shared__ __hip_bfloat16 xnb[NTOK][CH + 2];
    __shared__ float qs[NTOK][33], ks_[NTOK][33], vs[NTOK][33];
    __shared__ float ss[NTOK][NTOK + 1];
    __shared__ float mu[NTOK], rs[NTOK];

    float xreg[19];

    for (int idx = tid, k = 0; idx < NTOK * CH; idx += 256, ++k) {
        int c = idx / NTOK, n = idx % NTOK;
        int i = n / WSZ, j = n % WSZ;
        int h = wh * WSZ + i + SHIFT_; if (h >= HIMG) h -= HIMG;
        int w = ww * WSZ + j + SHIFT_; if (w >= WIMG) w -= WIMG;
        float v = x[((size_t)(b * CH + c) * HIMG + h) * WIMG + w];
        ao[n][c] = v; xreg[k] = v;
    }
    __syncthreads();
    if (tid < NTOK) {
        float s0 = 0.f, s1 = 0.f;
        for (int c = 0; c < CH; ++c) { float v = ao[tid][c]; s0 += v; s1 += v * v; }
        float m = s0 / CH;
        mu[tid] = m; rs[tid] = rsqrtf(s1 / CH - m * m + 1e-5f);
    }
    __syncthreads();
    for (int idx = tid; idx < NTOK * CH; idx += 256) {
        int c = idx / NTOK, n = idx % NTOK;
        xnb[n][c] = __float2bfloat16((ao[n][c] - mu[n]) * rs[n] * g1[c] + b1[c]);
    }
    __syncthreads();
    const float scale = 0.17677669529663687f;
    for (int hh = 0; hh < 3; ++hh) {
        for (int idx = tid; idx < 3 * 32 * NTOK; idx += 256) {
            int col = idx / NTOK, n = idx % NTOK;
            int which = col >> 5, d = col & 31;
            int gc = which * CH + hh * 32 + d;
            float acc = qkv_b[gc];
            for (int c = 0; c < CH; ++c)
                acc += __bfloat162float(xnb[n][c]) * qkv_w[c * 288 + gc];
            if (which == 0) qs[n][d] = acc;
            else if (which == 1) ks_[n][d] = acc;
            else vs[n][d] = acc;
        }
        __syncthreads();
        for (int idx = tid; idx < NTOK * NTOK; idx += 256) {
            int i = idx / NTOK, j = idx % NTOK;
            float acc = 0.f;
            for (int d = 0; d < 32; ++d) acc += qs[i][d] * ks_[j][d];
            int yi = i / WSZ, xi = i % WSZ, yj = j / WSZ, xj = j % WSZ;
            int rel = (yi - yj + 6) * 13 + (xi - xj + 6);
            ss[i][j] = acc * scale + btab[rel * 3 + hh];
        }
        __syncthreads();
        if (tid < NTOK) {
            float m = -1e30f;
            for (int j = 0; j < NTOK; ++j) m = fmaxf(m, ss[tid][j]);
            float sum = 0.f;
            for (int j = 0; j < NTOK; ++j) { float e = __expf(ss[tid][j] - m); ss[tid][j] = e; sum += e; }
            float inv = 1.f / sum;
            for (int j = 0; j < NTOK; ++j) ss[tid][j] *= inv;
        }
        __syncthreads();
        for (int idx = tid; idx < NTOK * 32; idx += 256) {
            int n = idx / 32, d = idx % 32;
            float acc = 0.f;
            for (int j = 0; j < NTOK; ++j) acc += ss[n][j] * vs[j][d];
            ao[n][hh * 32 + d] = acc;
        }
        __syncthreads();
    }
    for (int idx = tid, k = 0; idx < NTOK * CH; idx += 256, ++k) {
        int oc = idx / NTOK, n = idx % NTOK;
        int i = n / WSZ, j = n % WSZ;
        int h = wh * WSZ + i + SHIFT_; if (h >= HIMG) h -= HIMG;
        int w = ww * WSZ + j + SHIFT_; if (w >= WIMG) w -= WIMG;
        float acc = proj_b[oc];
        for (int cc = 0; cc < CH; ++cc) acc += ao[n][cc] * proj_w[cc * CH + oc];
        out[((size_t)(b * CH + oc) * HIMG + h) * WIMG + w] = xreg[k] + acc;
    }
}

__global__ __launch_bounds__(256) void mlp_fb_kernel(
    const float* __restrict__ g2, const float* __restrict__ b2,
    const float* __restrict__ w1, const float* __restrict__ bb1,
    const float* __restrict__ w2, const float* __restrict__ bb2,
    float* __restrict__ io)
{
    const int tid = threadIdx.x;
    const int b = blockIdx.x / 784;
    const int hw0 = (blockIdx.x % 784) * 64;

    __shared__ float xt[CH][64];
    __shared__ __hip_bfloat16 xn2[CH][66];
    __shared__ float hbuf[64][65];
    __shared__ float mu2[64], rs2[64];

    for (int idx = tid; idx < CH * 64; idx += 256) {
        int c = idx / 64, t = idx % 64;
        xt[c][t] = io[((size_t)(b * CH + c)) * HWIMG + hw0 + t];
    }
    __syncthreads();
    if (tid < 64) {
        float s0 = 0.f, s1 = 0.f;
        for (int c = 0; c < CH; ++c) { float v = xt[c][tid]; s0 += v; s1 += v * v; }
        float m = s0 / CH;
        mu2[tid] = m; rs2[tid] = rsqrtf(s1 / CH - m * m + 1e-5f);
    }
    __syncthreads();
    for (int idx = tid; idx < CH * 64; idx += 256) {
        int c = idx / 64, t = idx % 64;
        xn2[c][t] = __float2bfloat16((xt[c][t] - mu2[t]) * rs2[t] * g2[c] + b2[c]);
    }
    __syncthreads();
    const int tt = tid & 63, oc0 = tid >> 6;
    float acc[24];
    #pragma unroll
    for (int k = 0; k < 24; ++k) acc[k] = bb2[oc0 + 4 * k];
    for (int kc = 0; kc < HID; kc += 64) {
        for (int idx = tid; idx < 64 * 64; idx += 256) {
            int kk = idx / 64, t = idx % 64;
            float a = bb1[kc + kk];
            for (int c = 0; c < CH; ++c)
                a += __bfloat162float(xn2[c][t]) * w1[c * HID + kc + kk];
            hbuf[t][kk] = gelu_f(a);
        }
        __syncthreads();
        for (int kk = 0; kk < 64; ++kk) {
            float hv = hbuf[tt][kk];
            const float* wrow = &w2[(size_t)(kc + kk) * CH + oc0];
            #pragma unroll
            for (int k = 0; k < 24; ++k) acc[k] += hv * wrow[4 * k];
        }
        __syncthreads();
    }
    #pragma unroll
    for (int k = 0; k < 24; ++k) {
        int oc = oc0 + 4 * k;
        io[((size_t)(b * CH + oc)) * HWIMG + hw0 + tt] = xt[oc][tt] + acc[k];
    }
}

extern "C" void kernel_launch(void* const* d_in, const int* in_sizes, int n_in,
                              void* d_out, int out_size, void* d_ws, size_t ws_size,
                              hipStream_t stream) {
    const float* x    = (const float*)d_in[0];
    const float* n1g  = (const float*)d_in[1];
    const float* n1b  = (const float*)d_in[2];
    const float* qkvw = (const float*)d_in[3];
    const float* qkvb = (const float*)d_in[4];
    const float* pw   = (const float*)d_in[5];
    const float* pbv  = (const float*)d_in[6];
    const float* bt   = (const float*)d_in[7];
    const float* n2g  = (const float*)d_in[8];
    const float* n2b  = (const float*)d_in[9];
    const float* f1w  = (const float*)d_in[10];
    const float* f1b  = (const float*)d_in[11];
    const float* f2w  = (const float*)d_in[12];
    const float* f2b  = (const float*)d_in[13];
    float* out = (float*)d_out;

    const size_t FULL_NEED = 262144ull + 77070336ull;
    if (ws_size >= FULL_NEED) {
        __hip_bfloat16* wsW = (__hip_bfloat16*)d_ws;
        __hip_bfloat16* projout = (__hip_bfloat16*)((char*)d_ws + 262144);
        prep_kernel<<<477, 256, 0, stream>>>(f1w, f2w, pw, qkvw, wsW, 122112);
        attn2_kernel<<<2048, 256, 0, stream>>>(x, n1g, n1b, wsW, qkvb, pbv, bt, projout);
        mlp2_kernel<<<3136, 512, 0, stream>>>(x, projout, n2g, n2b, f1b, f2b, wsW, out);
    } else {
        attn_fb_kernel<<<8192, 256, 0, stream>>>(x, n1g, n1b, qkvw, qkvb, pw, pbv, bt, out);
        mlp_fb_kernel<<<8 * 784, 256, 0, stream>>>(n2g, n2b, f1w, f1b, f2w, f2b, out);
    }
}

// Round 15
// 397.001 us; speedup vs baseline: 1.2253x; 1.0248x over previous
//
#include <hip/hip_runtime.h>
#include <hip/hip_bf16.h>
#include <math.h>

#define WSZ 7
#define NTOK 49
#define CH 96
#define HIMG 224
#define WIMG 224
#define HWIMG (224*224)
#define SHIFT_ 3
#define HID 384

typedef __attribute__((ext_vector_type(8))) short bf16x8;
typedef __attribute__((ext_vector_type(4))) float f32x4;
typedef unsigned int u32;
typedef unsigned short u16;

__device__ __forceinline__ u32 pk2(float a, float b) {
    u16 ua = __builtin_bit_cast(u16, __float2bfloat16(a));
    u16 ub = __builtin_bit_cast(u16, __float2bfloat16(b));
    return (u32)ua | ((u32)ub << 16);
}
__device__ __forceinline__ float bflo(u32 u) { return __builtin_bit_cast(float, u << 16); }

union FragU { u32 w[4]; bf16x8 v; };

// regroup: C'-frags of two 16-row tiles (rows g*4+r, cols l15) -> A/B-frag
__device__ __forceinline__ bf16x8 regroup(u32 t0w0, u32 t0w1, u32 t1w0, u32 t1w1, int lane) {
    int sl0 = (lane & 15) + ((lane & 16) << 1);
    int sl1 = sl0 + 16;
    u32 x0 = (u32)__shfl((int)t0w0, sl0);
    u32 y0 = (u32)__shfl((int)t1w0, sl0);
    u32 x1 = (u32)__shfl((int)t0w1, sl0);
    u32 y1 = (u32)__shfl((int)t1w1, sl0);
    u32 x2 = (u32)__shfl((int)t0w0, sl1);
    u32 y2 = (u32)__shfl((int)t1w0, sl1);
    u32 x3 = (u32)__shfl((int)t0w1, sl1);
    u32 y3 = (u32)__shfl((int)t1w1, sl1);
    bool lo = lane < 32;
    FragU f;
    f.w[0] = lo ? x0 : y0;
    f.w[1] = lo ? x1 : y1;
    f.w[2] = lo ? x2 : y2;
    f.w[3] = lo ? x3 : y3;
    return f.v;
}

// tanh-approx GELU as x*sigmoid(2s): no division.
__device__ __forceinline__ float gelu_f(float x) {
    float x2 = x * x;
    float t  = x * (1.5957691216057308f + 0.07135481283587191f * x2);
    float e  = __expf(t);
    float r  = __builtin_amdgcn_rcpf(e + 1.0f);
    return x - x * r;
}

// ---------- prep (round-7 proven) ----------
__global__ __launch_bounds__(256) void prep_kernel(
    const float* __restrict__ w1, const float* __restrict__ w2,
    const float* __restrict__ pw, const float* __restrict__ qw,
    __hip_bfloat16* __restrict__ ws, int n)
{
    int i = blockIdx.x * 256 + threadIdx.x;
    if (i >= n) return;
    float val = 0.f;
    if (i < 81920) {
        int ch = i / 20480, r = i - ch * 20480;
        int half = r / 10240;
        int rr = r - half * 10240;
        if (rr < 9984) {
            int row = rr / 104, col = rr - row * 104;
            if (col < 96)
                val = (half == 0) ? w1[col * HID + ch * 96 + row]
                                  : w2[(size_t)(ch * 96 + col) * CH + row];
        }
    } else if (i < 92160) {
        int r = i - 81920;
        if (r < 9984) {
            int row = r / 104, col = r - row * 104;
            if (col < 96) val = pw[col * CH + row];
        }
    } else {
        int j = i - 92160;
        int hh = j / 9984, rr = j - hh * 9984;
        int dp = rr / 104, c = rr - dp * 104;
        if (c < 96) {
            int colW = (dp < 32) ? (hh * 32 + dp)
                     : (dp < 64) ? (96 + hh * 32 + dp - 32)
                                 : (192 + hh * 32 + dp - 64);
            val = qw[c * 288 + colW];
        }
    }
    ws[i] = __float2bfloat16(val);
}

// ========== K1 (round-10 structure + setprio + NONTEMPORAL streaming x / projout) ==========
__global__ __launch_bounds__(256) void attn2_kernel(
    const float* __restrict__ x,
    const float* __restrict__ g1, const float* __restrict__ b1,
    const __hip_bfloat16* __restrict__ wsW,
    const float* __restrict__ qkv_b, const float* __restrict__ pb,
    const float* __restrict__ btab,
    __hip_bfloat16* __restrict__ projout)
{
    const int tid  = threadIdx.x;
    const int lane = tid & 63;
    const int wv   = tid >> 6;
    const int l15  = lane & 15;
    const int g    = lane >> 4;
    const int bi   = blockIdx.x;
    const int b    = bi >> 8;            // 256 blocks per image
    const int wh   = (bi >> 3) & 31;
    const int ww0  = (bi & 7) * 4;       // first of 4 windows
    const int ww   = ww0 + wv;

    __shared__ float btabL[507];
    __shared__ __align__(16) char uniA[43008];   // strip xsb[96][7][32] bf16 | later per-wave 4x4608

    __hip_bfloat16 (*xsb)[7][32] = (__hip_bfloat16(*)[7][32])uniA;
    __hip_bfloat16 (*vT)[72] = (__hip_bfloat16(*)[72])(uniA + wv * 4608);
    u32* prS = (u32*)(uniA + wv * 4608);

    for (int idx = tid; idx < 507; idx += 256) btabL[idx] = btab[idx];

    // ---- cooperative stage: shifted strip rows [wh*7+3 .. +9], cols aligned 32 ----
    // x is read-once streaming data: nontemporal so it doesn't evict the L2-resident weights.
    const int colBase = ww0 * 7 + 3;
    const int cA  = colBase & ~3;
    const int cb4 = cA >> 2;
    const int a0  = colBase & 3;
    #pragma unroll
    for (int k = 0; k < 21; ++k) {       // 96*7*8 float4 / 256 threads
        int idx = tid + 256 * k;
        int c = idx / 56, rem = idx - c * 56;
        int r = rem >> 3, cf = rem & 7;
        int gr = wh * 7 + 3 + r; if (gr >= HIMG) gr -= HIMG;
        int g4 = cb4 + cf; if (g4 >= 56) g4 -= 56;
        f32x4 v = __builtin_nontemporal_load(
            (const f32x4*)(x + ((size_t)(b * CH + c) * HIMG + gr) * WIMG + g4 * 4));
        uint2 pk;
        pk.x = pk2(v[0], v[1]);
        pk.y = pk2(v[2], v[3]);
        *(uint2*)&xsb[c][r][cf * 4] = pk;
    }
    __syncthreads();

    // ---- LN1: xn B-fragments fully in registers (reads from LDS strip) ----
    bf16x8 xB[4][3];
    #pragma unroll
    for (int it = 0; it < 4; ++it) {
        int i = it * 16 + l15;
        bool real = i < NTOK;
        int yi = i / 7, xi = i - yi * 7;
        int sc = a0 + wv * 7 + xi;
        float raw[24];
        float s0 = 0.f, s1 = 0.f;
        #pragma unroll
        for (int ks = 0; ks < 3; ++ks)
            #pragma unroll
            for (int t = 0; t < 8; ++t) {
                int c = ks * 32 + g * 8 + t;
                float v = real ? __bfloat162float(xsb[c][yi][sc]) : 0.f;
                raw[ks * 8 + t] = v; s0 += v; s1 += v * v;
            }
        s0 += __shfl_xor(s0, 16); s0 += __shfl_xor(s0, 32);
        s1 += __shfl_xor(s1, 16); s1 += __shfl_xor(s1, 32);
        float mu = s0 * (1.0f / CH);
        float rstd = rsqrtf(s1 * (1.0f / CH) - mu * mu + 1e-5f);
        #pragma unroll
        for (int ks = 0; ks < 3; ++ks)
            #pragma unroll
            for (int t = 0; t < 8; ++t) {
                int c = ks * 32 + g * 8 + t;
                float xv = real ? ((raw[ks * 8 + t] - mu) * rstd * g1[c] + b1[c]) : 0.f;
                xB[it][ks][t] = (short)__builtin_bit_cast(u16, __float2bfloat16(xv));
            }
    }
    __syncthreads();   // strip dead; per-wave scratch (vT/prS) may now overwrite uniA

    const float scale = 0.17677669529663687f;
    bf16x8 aoB[3][4];

    for (int h = 0; h < 3; ++h) {
        const __hip_bfloat16* qkvTg = wsW + 92160 + h * 9984;

        float qb[2][4], kb[2][4], vb[2][4];
        #pragma unroll
        for (int dt = 0; dt < 2; ++dt)
            #pragma unroll
            for (int r = 0; r < 4; ++r) {
                int d = h * 32 + dt * 16 + g * 4 + r;
                qb[dt][r] = qkv_b[d];
                kb[dt][r] = qkv_b[96 + d];
                vb[dt][r] = qkv_b[192 + d];
            }

        // ---- Q (direct L2 weight frags) ----
        __builtin_amdgcn_s_setprio(1);
        u32 Qpk[2][4][2];
        #pragma unroll
        for (int dt = 0; dt < 2; ++dt) {
            const __hip_bfloat16* wr = qkvTg + (dt * 16 + l15) * 104 + g * 8;
            bf16x8 a0f = *(const bf16x8*)(wr);
            bf16x8 a1f = *(const bf16x8*)(wr + 32);
            bf16x8 a2f = *(const bf16x8*)(wr + 64);
            #pragma unroll
            for (int it = 0; it < 4; ++it) {
                f32x4 c4 = {0.f, 0.f, 0.f, 0.f};
                c4 = __builtin_amdgcn_mfma_f32_16x16x32_bf16(a0f, xB[it][0], c4, 0, 0, 0);
                c4 = __builtin_amdgcn_mfma_f32_16x16x32_bf16(a1f, xB[it][1], c4, 0, 0, 0);
                c4 = __builtin_amdgcn_mfma_f32_16x16x32_bf16(a2f, xB[it][2], c4, 0, 0, 0);
                Qpk[dt][it][0] = pk2(c4[0] + qb[dt][0], c4[1] + qb[dt][1]);
                Qpk[dt][it][1] = pk2(c4[2] + qb[dt][2], c4[3] + qb[dt][3]);
            }
        }
        bf16x8 QB[4];
        #pragma unroll
        for (int it = 0; it < 4; ++it)
            QB[it] = regroup(Qpk[0][it][0], Qpk[0][it][1], Qpk[1][it][0], Qpk[1][it][1], lane);

        // ---- K ----
        u32 Kpk[2][4][2];
        #pragma unroll
        for (int dt = 0; dt < 2; ++dt) {
            const __hip_bfloat16* wr = qkvTg + (32 + dt * 16 + l15) * 104 + g * 8;
            bf16x8 a0f = *(const bf16x8*)(wr);
            bf16x8 a1f = *(const bf16x8*)(wr + 32);
            bf16x8 a2f = *(const bf16x8*)(wr + 64);
            #pragma unroll
            for (int it = 0; it < 4; ++it) {
                f32x4 c4 = {0.f, 0.f, 0.f, 0.f};
                c4 = __builtin_amdgcn_mfma_f32_16x16x32_bf16(a0f, xB[it][0], c4, 0, 0, 0);
                c4 = __builtin_amdgcn_mfma_f32_16x16x32_bf16(a1f, xB[it][1], c4, 0, 0, 0);
                c4 = __builtin_amdgcn_mfma_f32_16x16x32_bf16(a2f, xB[it][2], c4, 0, 0, 0);
                Kpk[dt][it][0] = pk2(c4[0] + kb[dt][0], c4[1] + kb[dt][1]);
                Kpk[dt][it][1] = pk2(c4[2] + kb[dt][2], c4[3] + kb[dt][3]);
            }
        }
        bf16x8 KA[4];
        #pragma unroll
        for (int it = 0; it < 4; ++it)
            KA[it] = regroup(Kpk[0][it][0], Kpk[0][it][1], Kpk[1][it][0], Kpk[1][it][1], lane);

        // ---- V -> vT (per-wave LDS) ----
        #pragma unroll
        for (int dt = 0; dt < 2; ++dt) {
            const __hip_bfloat16* wr = qkvTg + (64 + dt * 16 + l15) * 104 + g * 8;
            bf16x8 a0f = *(const bf16x8*)(wr);
            bf16x8 a1f = *(const bf16x8*)(wr + 32);
            bf16x8 a2f = *(const bf16x8*)(wr + 64);
            #pragma unroll
            for (int it = 0; it < 4; ++it) {
                f32x4 c4 = {0.f, 0.f, 0.f, 0.f};
                c4 = __builtin_amdgcn_mfma_f32_16x16x32_bf16(a0f, xB[it][0], c4, 0, 0, 0);
                c4 = __builtin_amdgcn_mfma_f32_16x16x32_bf16(a1f, xB[it][1], c4, 0, 0, 0);
                c4 = __builtin_amdgcn_mfma_f32_16x16x32_bf16(a2f, xB[it][2], c4, 0, 0, 0);
                #pragma unroll
                for (int r = 0; r < 4; ++r)
                    vT[dt * 16 + g * 4 + r][it * 16 + l15] = __float2bfloat16(c4[r] + vb[dt][r]);
            }
        }
        __builtin_amdgcn_s_setprio(0);
        bf16x8 VBf[2][2];
        #pragma unroll
        for (int dt = 0; dt < 2; ++dt)
            #pragma unroll
            for (int ks = 0; ks < 2; ++ks)
                VBf[dt][ks] = *(const bf16x8*)&vT[dt * 16 + l15][ks * 32 + g * 8];

        // ---- i-tiles: scores + softmax + PV -> aoB frags ----
        #pragma unroll
        for (int it = 0; it < 4; ++it) {
            __builtin_amdgcn_s_setprio(1);
            f32x4 SC[4];
            #pragma unroll
            for (int jt = 0; jt < 4; ++jt) {
                f32x4 z = {0.f, 0.f, 0.f, 0.f};
                SC[jt] = __builtin_amdgcn_mfma_f32_16x16x32_bf16(KA[jt], QB[it], z, 0, 0, 0);
            }
            __builtin_amdgcn_s_setprio(0);
            int i = it * 16 + l15;
            int yi = i / 7, xi = i - yi * 7;
            float p[16];
            float m = -1e30f;
            #pragma unroll
            for (int jt = 0; jt < 4; ++jt)
                #pragma unroll
                for (int r = 0; r < 4; ++r) {
                    int j = jt * 16 + g * 4 + r;
                    int yj = j / 7, xj = j - yj * 7;
                    int rel = (yi - yj + 6) * 13 + (xi - xj + 6);
                    rel = rel < 0 ? 0 : (rel > 168 ? 168 : rel);
                    float s = (j < NTOK) ? (SC[jt][r] * scale + btabL[rel * 3 + h]) : -1e30f;
                    p[jt * 4 + r] = s;
                    m = fmaxf(m, s);
                }
            m = fmaxf(m, __shfl_xor(m, 16));
            m = fmaxf(m, __shfl_xor(m, 32));
            float sum = 0.f;
            #pragma unroll
            for (int q = 0; q < 16; ++q) { float e = __expf(p[q] - m); p[q] = e; sum += e; }
            sum += __shfl_xor(sum, 16);
            sum += __shfl_xor(sum, 32);
            float inv = 1.f / sum;
            u32 Ppk[4][2];
            #pragma unroll
            for (int jt = 0; jt < 4; ++jt) {
                Ppk[jt][0] = pk2(p[jt * 4 + 0] * inv, p[jt * 4 + 1] * inv);
                Ppk[jt][1] = pk2(p[jt * 4 + 2] * inv, p[jt * 4 + 3] * inv);
            }
            bf16x8 PA0 = regroup(Ppk[0][0], Ppk[0][1], Ppk[1][0], Ppk[1][1], lane);
            bf16x8 PA1 = regroup(Ppk[2][0], Ppk[2][1], Ppk[3][0], Ppk[3][1], lane);
            u32 opk[2][2];
            __builtin_amdgcn_s_setprio(1);
            #pragma unroll
            for (int dt = 0; dt < 2; ++dt) {
                f32x4 o = {0.f, 0.f, 0.f, 0.f};
                o = __builtin_amdgcn_mfma_f32_16x16x32_bf16(PA0, VBf[dt][0], o, 0, 0, 0);
                o = __builtin_amdgcn_mfma_f32_16x16x32_bf16(PA1, VBf[dt][1], o, 0, 0, 0);
                opk[dt][0] = pk2(o[0], o[1]);
                opk[dt][1] = pk2(o[2], o[3]);
            }
            __builtin_amdgcn_s_setprio(0);
            aoB[h][it] = regroup(opk[0][0], opk[0][1], opk[1][0], opk[1][1], lane);
        }
    }

    // ---- proj per it-tile (pwT direct from L2): C'[oc][tok] -> per-wave LDS -> nt store ----
    const __hip_bfloat16* pwTg = wsW + 81920;
    for (int it = 0; it < 4; ++it) {
        __builtin_amdgcn_s_setprio(1);
        #pragma unroll
        for (int mt = 0; mt < 6; ++mt) {
            const __hip_bfloat16* wr = pwTg + (mt * 16 + l15) * 104 + g * 8;
            f32x4 cp = {0.f, 0.f, 0.f, 0.f};
            #pragma unroll
            for (int ks = 0; ks < 3; ++ks) {
                bf16x8 af = *(const bf16x8*)(wr + ks * 32);
                cp = __builtin_amdgcn_mfma_f32_16x16x32_bf16(af, aoB[ks][it], cp, 0, 0, 0);
            }
            float v0 = cp[0] + pb[mt * 16 + g * 4 + 0];
            float v1 = cp[1] + pb[mt * 16 + g * 4 + 1];
            float v2 = cp[2] + pb[mt * 16 + g * 4 + 2];
            float v3 = cp[3] + pb[mt * 16 + g * 4 + 3];
            prS[l15 * 52 + mt * 8 + g * 2 + 0] = pk2(v0, v1);
            prS[l15 * 52 + mt * 8 + g * 2 + 1] = pk2(v2, v3);
        }
        __builtin_amdgcn_s_setprio(0);
        #pragma unroll
        for (int s = 0; s < 3; ++s) {
            int chunk = lane + 64 * s;
            int row = chunk / 12, q = chunk - row * 12;
            int tok = it * 16 + row;
            if (tok < NTOK) {
                int yi = tok / 7, xi = tok - yi * 7;
                int hh = wh * 7 + yi + SHIFT_; if (hh >= HIMG) hh -= HIMG;
                int wp = ww * 7 + xi + SHIFT_; if (wp >= WIMG) wp -= WIMG;
                f32x4 val = *(const f32x4*)((const char*)prS + row * 208 + q * 16);
                __builtin_nontemporal_store(val,
                    (f32x4*)(projout + ((size_t)b * HWIMG + hh * WIMG + wp) * 96 + q * 8));
            }
        }
    }
}

// ========== K2 v5 (round-10 proven) + NONTEMPORAL streaming x / projout / out ==========
#define LDSTG(p0, p1, p2, s) { const float4* _s = wsrc + (s) * 1280; \
    p0 = _s[tid]; p1 = _s[tid + 512]; if (tid < 256) p2 = _s[tid + 1024]; }
#define WRSTG(p0, p1, p2, off) { float4* _d = (float4*)(SB + (off)); \
    _d[tid] = p0; _d[tid + 512] = p1; if (tid < 256) _d[tid + 1024] = p2; }

__global__ __launch_bounds__(512, 4) void mlp2_kernel(
    const float* __restrict__ x, const __hip_bfloat16* __restrict__ projout,
    const float* __restrict__ g2, const float* __restrict__ b2,
    const float* __restrict__ bb1, const float* __restrict__ bb2,
    const __hip_bfloat16* __restrict__ wsW,
    float* __restrict__ out)
{
    const int tid = threadIdx.x;
    const int lane = tid & 63, wv = tid >> 6;
    const int l15 = lane & 15, g = lane >> 4;
    const int b = blockIdx.x / 392;
    const int hw0 = (blockIdx.x % 392) * 128;
    const int tok = wv * 16 + l15;

    __shared__ __align__(16) char SB[50688];
    __shared__ float bb1S[HID];

    __hip_bfloat16 (*xnS)[104] = (__hip_bfloat16(*)[104])SB;
    __hip_bfloat16 (*wT0)[104] = (__hip_bfloat16(*)[104])SB;
    __hip_bfloat16 (*wT1)[104] = (__hip_bfloat16(*)[104])(SB + 20480);
    float* ob = (float*)SB;

    const float4* wsrc = (const float4*)wsW;
    float4 ra0, ra1, ra2, rb0, rb1, rb2;

    LDSTG(ra0, ra1, ra2, 0);

    #pragma unroll
    for (int s = 0; s < 3; ++s) {
        int chunk = tid + 512 * s;
        int row = chunk / 12, q = chunk - row * 12;
        f32x4 ld = __builtin_nontemporal_load(
            (const f32x4*)(projout + ((size_t)b * HWIMG + hw0 + row) * 96 + q * 8));
        *(f32x4*)&xnS[row][q * 8] = ld;
    }
    for (int idx = tid; idx < HID; idx += 512) bb1S[idx] = bb1[idx];
    __syncthreads();

    float xr[24];
    float s0 = 0.f, s1 = 0.f;
    bf16x8 pf[3];
    #pragma unroll
    for (int ks = 0; ks < 3; ++ks)
        pf[ks] = *(const bf16x8*)&xnS[tok][ks * 32 + g * 8];
    const float* xb = x + (size_t)(b * CH) * HWIMG + hw0 + tok;
    #pragma unroll
    for (int ks = 0; ks < 3; ++ks)
        #pragma unroll
        for (int j = 0; j < 8; ++j) {
            int c = ks * 32 + g * 8 + j;
            float xv = __builtin_nontemporal_load(&xb[(size_t)c * HWIMG]);
            float v = xv + bflo((u32)(u16)pf[ks][j]);
            xr[ks * 8 + j] = v; s0 += v; s1 += v * v;
        }
    s0 += __shfl_xor(s0, 16); s0 += __shfl_xor(s0, 32);
    s1 += __shfl_xor(s1, 16); s1 += __shfl_xor(s1, 32);
    float mu = s0 * (1.0f / CH);
    float rstd = rsqrtf(s1 * (1.0f / CH) - mu * mu + 1e-5f);

    bf16x8 xbf[3];
    #pragma unroll
    for (int ks = 0; ks < 3; ++ks) {
        float nv[8];
        #pragma unroll
        for (int j = 0; j < 8; ++j) {
            int c = ks * 32 + g * 8 + j;
            nv[j] = (xr[ks * 8 + j] - mu) * rstd * g2[c] + b2[c];
        }
        FragU f;
        f.w[0] = pk2(nv[0], nv[1]); f.w[1] = pk2(nv[2], nv[3]);
        f.w[2] = pk2(nv[4], nv[5]); f.w[3] = pk2(nv[6], nv[7]);
        xbf[ks] = f.v;
    }
    __syncthreads();

    WRSTG(ra0, ra1, ra2, 0);
    LDSTG(rb0, rb1, rb2, 1);
    __syncthreads();

    f32x4 acc[6];
    #pragma unroll
    for (int mt = 0; mt < 6; ++mt) {
        #pragma unroll
        for (int r = 0; r < 4; ++r) acc[mt][r] = bb2[mt * 16 + g * 4 + r];
    }

    #pragma unroll
    for (int ch = 0; ch < 4; ++ch) {
        u32 hpk[6][2];
        #pragma unroll
        for (int mt = 0; mt < 6; ++mt) {
            f32x4 f = {0.f, 0.f, 0.f, 0.f};
            #pragma unroll
            for (int ks = 0; ks < 3; ++ks) {
                bf16x8 af = *(const bf16x8*)&wT0[mt * 16 + l15][ks * 32 + g * 8];
                f = __builtin_amdgcn_mfma_f32_16x16x32_bf16(af, xbf[ks], f, 0, 0, 0);
            }
            float gl[4];
            #pragma unroll
            for (int r = 0; r < 4; ++r) {
                float a = f[r] + bb1S[ch * 96 + mt * 16 + g * 4 + r];
                gl[r] = gelu_f(a);
            }
            hpk[mt][0] = pk2(gl[0], gl[1]);
            hpk[mt][1] = pk2(gl[2], gl[3]);
        }
        WRSTG(rb0, rb1, rb2, 20480);
        __syncthreads();
        if (ch < 3) LDSTG(ra0, ra1, ra2, 2 * ch + 2);

        bf16x8 hf[3];
        hf[0] = regroup(hpk[0][0], hpk[0][1], hpk[1][0], hpk[1][1], lane);
        hf[1] = regroup(hpk[2][0], hpk[2][1], hpk[3][0], hpk[3][1], lane);
        hf[2] = regroup(hpk[4][0], hpk[4][1], hpk[5][0], hpk[5][1], lane);
        #pragma unroll
        for (int mt = 0; mt < 6; ++mt) {
            #pragma unroll
            for (int ks = 0; ks < 3; ++ks) {
                bf16x8 af = *(const bf16x8*)&wT1[mt * 16 + l15][ks * 32 + g * 8];
                acc[mt] = __builtin_amdgcn_mfma_f32_16x16x32_bf16(af, hf[ks], acc[mt], 0, 0, 0);
            }
        }
        if (ch < 3) WRSTG(ra0, ra1, ra2, 0);
        __syncthreads();
        if (ch < 3) LDSTG(rb0, rb1, rb2, 2 * ch + 3);
    }

    #pragma unroll
    for (int ks = 0; ks < 3; ++ks)
        #pragma unroll
        for (int j = 0; j < 8; ++j)
            ob[tok * 99 + ks * 32 + g * 8 + j] = xr[ks * 8 + j];
    __syncthreads();
    #pragma unroll
    for (int mt = 0; mt < 6; ++mt)
        #pragma unroll
        for (int r = 0; r < 4; ++r)
            ob[tok * 99 + mt * 16 + g * 4 + r] += acc[mt][r];
    __syncthreads();
    #pragma unroll
    for (int k = 0; k < 24; ++k) {
        int idx = tid + 512 * k;
        int c = idx >> 7, t = idx & 127;
        __builtin_nontemporal_store(ob[t * 99 + c],
            &out[(size_t)(b * CH + c) * HWIMG + hw0 + t]);
    }
}

// ================= FALLBACK (minimal, correct): used only if ws too small =================
__global__ __launch_bounds__(256) void attn_fb_kernel(
    const float* __restrict__ x,
    const float* __restrict__ g1, const float* __restrict__ b1,
    const float* __restrict__ qkv_w, const float* __restrict__ qkv_b,
    const float* __restrict__ proj_w, const float* __restrict__ proj_b,
    const float* __restrict__ btab,
    float* __restrict__ out)
{
    const int tid = threadIdx.x;
    const int wid = blockIdx.x;
    const int b  = wid >> 10;
    const int wh = (wid >> 5) & 31;
    const int ww = wid & 31;

    __shared__ float ao[NTOK][CH + 1];
    __shared__ __hip_bfloat16 xnb[NTOK][CH + 2];
    __shared__ float qs[NTOK][33], ks_[NTOK][33], vs[NTOK][33];
    __shared__ float ss[NTOK][NTOK + 1];
    __shared__ float mu[NTOK], rs[NTOK];

    float xreg[19];

    for (int idx = tid, k = 0; idx < NTOK * CH; idx += 256, ++k) {
        int c = idx / NTOK, n = idx % NTOK;
        int i = n / WSZ, j = n % WSZ;
        int h = wh * WSZ + i + SHIFT_; if (h >= HIMG) h -= HIMG;
        int w = ww * WSZ + j + SHIFT_; if (w >= WIMG) w -= WIMG;
        float v = x[((size_t)(b * CH + c) * HIMG + h) * WIMG + w];
        ao[n][c] = v; xreg[k] = v;
    }
    __syncthreads();
    if (tid < NTOK) {
        float s0 = 0.f, s1 = 0.f;
        for (int c = 0; c < CH; ++c) { float v = ao[tid][c]; s0 += v; s1 += v * v; }
        float m = s0 / CH;
        mu[tid] = m; rs[tid] = rsqrtf(s1 / CH - m * m + 1e-5f);
    }
    __syncthreads();
    for (int idx = tid; idx < NTOK * CH; idx += 256) {
        int c = idx / NTOK, n = idx % NTOK;
        xnb[n][c] = __float2bfloat16((ao[n][c] - mu[n]) * rs[n] * g1[c] + b1[c]);
    }
    __syncthreads();
    const float scale = 0.17677669529663687f;
    for (int hh = 0; hh < 3; ++hh) {
        for (int idx = tid; idx < 3 * 32 * NTOK; idx += 256) {
            int col = idx / NTOK, n = idx % NTOK;
            int which = col >> 5, d = col & 31;
            int gc = which * CH + hh * 32 + d;
            float acc = qkv_b[gc];
            for (int c = 0; c < CH; ++c)
                acc += __bfloat162float(xnb[n][c]) * qkv_w[c * 288 + gc];
            if (which == 0) qs[n][d] = acc;
            else if (which == 1) ks_[n][d] = acc;
            else vs[n][d] = acc;
        }
        __syncthreads();
        for (int idx = tid; idx < NTOK * NTOK; idx += 256) {
            int i = idx / NTOK, j = idx % NTOK;
            float acc = 0.f;
            for (int d = 0; d < 32; ++d) acc += qs[i][d] * ks_[j][d];
            int yi = i / WSZ, xi = i % WSZ, yj = j / WSZ, xj = j % WSZ;
            int rel = (yi - yj + 6) * 13 + (xi - xj + 6);
            ss[i][j] = acc * scale + btab[rel * 3 + hh];
        }
        __syncthreads();
        if (tid < NTOK) {
            float m = -1e30f;
            for (int j = 0; j < NTOK; ++j) m = fmaxf(m, ss[tid][j]);
            float sum = 0.f;
            for (int j = 0; j < NTOK; ++j) { float e = __expf(ss[tid][j] - m); ss[tid][j] = e; sum += e; }
            float inv = 1.f / sum;
            for (int j = 0; j < NTOK; ++j) ss[tid][j] *= inv;
        }
        __syncthreads();
        for (int idx = tid; idx < NTOK * 32; idx += 256) {
            int n = idx / 32, d = idx % 32;
            float acc = 0.f;
            for (int j = 0; j < NTOK; ++j) acc += ss[n][j] * vs[j][d];
            ao[n][hh * 32 + d] = acc;
        }
        __syncthreads();
    }
    for (int idx = tid, k = 0; idx < NTOK * CH; idx += 256, ++k) {
        int oc = idx / NTOK, n = idx % NTOK;
        int i = n / WSZ, j = n % WSZ;
        int h = wh * WSZ + i + SHIFT_; if (h >= HIMG) h -= HIMG;
        int w = ww * WSZ + j + SHIFT_; if (w >= WIMG) w -= WIMG;
        float acc = proj_b[oc];
        for (int cc = 0; cc < CH; ++cc) acc += ao[n][cc] * proj_w[cc * CH + oc];
        out[((size_t)(b * CH + oc) * HIMG + h) * WIMG + w] = xreg[k] + acc;
    }
}

__global__ __launch_bounds__(256) void mlp_fb_kernel(
    const float* __restrict__ g2, const float* __restrict__ b2,
    const float* __restrict__ w1, const float* __restrict__ bb1,
    const float* __restrict__ w2, const float* __restrict__ bb2,
    float* __restrict__ io)
{
    const int tid = threadIdx.x;
    const int b = blockIdx.x / 784;
    const int hw0 = (blockIdx.x % 784) * 64;

    __shared__ float xt[CH][64];
    __shared__ __hip_bfloat16 xn2[CH][66];
    __shared__ float hbuf[64][65];
    __shared__ float mu2[64], rs2[64];

    for (int idx = tid; idx < CH * 64; idx += 256) {
        int c = idx / 64, t = idx % 64;
        xt[c][t] = io[((size_t)(b * CH + c)) * HWIMG + hw0 + t];
    }
    __syncthreads();
    if (tid < 64) {
        float s0 = 0.f, s1 = 0.f;
        for (int c = 0; c < CH; ++c) { float v = xt[c][tid]; s0 += v; s1 += v * v; }
        float m = s0 / CH;
        mu2[tid] = m; rs2[tid] = rsqrtf(s1 / CH - m * m + 1e-5f);
    }
    __syncthreads();
    for (int idx = tid; idx < CH * 64; idx += 256) {
        int c = idx / 64, t = idx % 64;
        xn2[c][t] = __float2bfloat16((xt[c][t] - mu2[t]) * rs2[t] * g2[c] + b2[c]);
    }
    __syncthreads();
    const int tt = tid & 63, oc0 = tid >> 6;
    float acc[24];
    #pragma unroll
    for (int k = 0; k < 24; ++k) acc[k] = bb2[oc0 + 4 * k];
    for (int kc = 0; kc < HID; kc += 64) {
        for (int idx = tid; idx < 64 * 64; idx += 256) {
            int kk = idx / 64, t = idx % 64;
            float a = bb1[kc + kk];
            for (int c = 0; c < CH; ++c)
                a += __bfloat162float(xn2[c][t]) * w1[c * HID + kc + kk];
            hbuf[t][kk] = gelu_f(a);
        }
        __syncthreads();
        for (int kk = 0; kk < 64; ++kk) {
            float hv = hbuf[tt][kk];
            const float* wrow = &w2[(size_t)(kc + kk) * CH + oc0];
            #pragma unroll
            for (int k = 0; k < 24; ++k) acc[k] += hv * wrow[4 * k];
        }
        __syncthreads();
    }
    #pragma unroll
    for (int k = 0; k < 24; ++k) {
        int oc = oc0 + 4 * k;
        io[((size_t)(b * CH + oc)) * HWIMG + hw0 + tt] = xt[oc][tt] + acc[k];
    }
}

extern "C" void kernel_launch(void* const* d_in, const int* in_sizes, int n_in,
                              void* d_out, int out_size, void* d_ws, size_t ws_size,
                              hipStream_t stream) {
    const float* x    = (const float*)d_in[0];
    const float* n1g  = (const float*)d_in[1];
    const float* n1b  = (const float*)d_in[2];
    const float* qkvw = (const float*)d_in[3];
    const float* qkvb = (const float*)d_in[4];
    const float* pw   = (const float*)d_in[5];
    const float* pbv  = (const float*)d_in[6];
    const float* bt   = (const float*)d_in[7];
    const float* n2g  = (const float*)d_in[8];
    const float* n2b  = (const float*)d_in[9];
    const float* f1w  = (const float*)d_in[10];
    const float* f1b  = (const float*)d_in[11];
    const float* f2w  = (const float*)d_in[12];
    const float* f2b  = (const float*)d_in[13];
    float* out = (float*)d_out;

    const size_t FULL_NEED = 262144ull + 77070336ull;
    if (ws_size >= FULL_NEED) {
        __hip_bfloat16* wsW = (__hip_bfloat16*)d_ws;
        __hip_bfloat16* projout = (__hip_bfloat16*)((char*)d_ws + 262144);
        prep_kernel<<<477, 256, 0, stream>>>(f1w, f2w, pw, qkvw, wsW, 122112);
        attn2_kernel<<<2048, 256, 0, stream>>>(x, n1g, n1b, wsW, qkvb, pbv, bt, projout);
        mlp2_kernel<<<3136, 512, 0, stream>>>(x, projout, n2g, n2b, f1b, f2b, wsW, out);
    } else {
        attn_fb_kernel<<<8192, 256, 0, stream>>>(x, n1g, n1b, qkvw, qkvb, pw, pbv, bt, out);
        mlp_fb_kernel<<<8 * 784, 256, 0, stream>>>(n2g, n2b, f1w, f1b, f2w, f2b, out);
    }
}